// Round 1
// baseline (2987.895 us; speedup 1.0000x reference)
//
#include <hip/hip_runtime.h>
#include <hip/hip_bf16.h>

#define NDIM 256   // IN_DIM
#define HDIM 128   // HID

// ---------------- degree ----------------
__global__ __launch_bounds__(256) void k_init_deg(float* __restrict__ deg, int n) {
    int i = blockIdx.x * 256 + threadIdx.x;
    if (i < n) deg[i] = 1.0f;  // self-loop
}

__global__ __launch_bounds__(256) void k_count_deg(const int* __restrict__ col,
                                                   float* __restrict__ deg, int E) {
    int e = blockIdx.x * 256 + threadIdx.x;
    if (e < E) atomicAdd(&deg[col[e]], 1.0f);
}

// ---------------- dinv + self-loop init of z accumulator ----------------
// idx over n*32; each thread handles one float4 of one node's h row.
__global__ __launch_bounds__(256) void k_selfloop(const float* __restrict__ deg,
                                                  float* __restrict__ dinv,
                                                  const float* __restrict__ h,
                                                  float* __restrict__ zacc, int n) {
    int idx = blockIdx.x * 256 + threadIdx.x;
    int node = idx >> 5, q = idx & 31;
    if (node >= n) return;
    float di = rsqrtf(deg[node]);
    if (q == 0) dinv[node] = di;
    float s = di * di;
    const float4 v = *reinterpret_cast<const float4*>(&h[(size_t)node * HDIM + q * 4]);
    float4 o;
    o.x = v.x * s; o.y = v.y * s; o.z = v.z * s; o.w = v.w * s;
    *reinterpret_cast<float4*>(&zacc[(size_t)node * HDIM + q * 4]) = o;
}

// ---------------- edge aggregation (atomic scatter) ----------------
// 32 lanes per edge, float4 per lane over HDIM=128 feats.
__global__ __launch_bounds__(256) void k_edge_agg(const int* __restrict__ row,
                                                  const int* __restrict__ col,
                                                  const float* __restrict__ h,
                                                  const float* __restrict__ dinv,
                                                  float* __restrict__ zacc, int E) {
    int idx = blockIdx.x * 256 + threadIdx.x;
    int e = idx >> 5, q = idx & 31;
    if (e >= E) return;
    int r = row[e], c = col[e];
    float nrm = dinv[r] * dinv[c];
    const float4 v = *reinterpret_cast<const float4*>(&h[(size_t)r * HDIM + q * 4]);
    float* dst = &zacc[(size_t)c * HDIM + q * 4];
    atomicAdd(dst + 0, v.x * nrm);
    atomicAdd(dst + 1, v.y * nrm);
    atomicAdd(dst + 2, v.z * nrm);
    atomicAdd(dst + 3, v.w * nrm);
}

// ---------------- bias + relu (in place on z) ----------------
__global__ __launch_bounds__(256) void k_bias_relu(float* __restrict__ z,
                                                   const float* __restrict__ b, int n32) {
    int idx = blockIdx.x * 256 + threadIdx.x;
    if (idx >= n32) return;
    int q = idx & 31;
    float4 v = *reinterpret_cast<float4*>(&z[(size_t)idx * 4]);
    const float4 bb = *reinterpret_cast<const float4*>(&b[q * 4]);
    v.x = fmaxf(v.x + bb.x, 0.f);
    v.y = fmaxf(v.y + bb.y, 0.f);
    v.z = fmaxf(v.z + bb.z, 0.f);
    v.w = fmaxf(v.w + bb.w, 0.f);
    *reinterpret_cast<float4*>(&z[(size_t)idx * 4]) = v;
}

// ---------------- tiled f32 GEMM:  C[r][c] = sum_k A[r][k]*W[c][k] (+bias[c]) ----------------
// block: 256 threads, tile 64 rows x 64 cols, K-chunk 32. 4x4 register blocking.
__global__ __launch_bounds__(256) void k_gemm_nt(const float* __restrict__ A,
                                                 const float* __restrict__ W,
                                                 const float* __restrict__ bias,
                                                 float* __restrict__ C,
                                                 int nrows, int K, int ncols) {
    __shared__ __align__(16) float As[32][68];  // [k][row], padded stride 68
    __shared__ __align__(16) float Ws[32][68];  // [k][col]
    const int t = threadIdx.x;
    const long long row_tile = (long long)blockIdx.x * 64;
    const int col_tile = blockIdx.y * 64;
    const int tx = t & 15, ty = t >> 4;
    const int r0 = ty * 4, c0 = tx * 4;
    float acc[4][4] = {};
    const int lr = t >> 2;          // 0..63 row/col being loaded
    const int lk = (t & 3) * 4;     // k offset; second load at +16

    for (int k0 = 0; k0 < K; k0 += 32) {
        long long gr = row_tile + lr;
        if (gr >= nrows) gr = nrows - 1;
        const float* asrc = &A[gr * (long long)K + k0 + lk];
        float4 a0 = *reinterpret_cast<const float4*>(asrc);
        float4 a1 = *reinterpret_cast<const float4*>(asrc + 16);
        const float* wsrc = &W[(long long)(col_tile + lr) * K + k0 + lk];
        float4 w0 = *reinterpret_cast<const float4*>(wsrc);
        float4 w1 = *reinterpret_cast<const float4*>(wsrc + 16);
        As[lk + 0][lr] = a0.x; As[lk + 1][lr] = a0.y; As[lk + 2][lr] = a0.z; As[lk + 3][lr] = a0.w;
        As[lk + 16][lr] = a1.x; As[lk + 17][lr] = a1.y; As[lk + 18][lr] = a1.z; As[lk + 19][lr] = a1.w;
        Ws[lk + 0][lr] = w0.x; Ws[lk + 1][lr] = w0.y; Ws[lk + 2][lr] = w0.z; Ws[lk + 3][lr] = w0.w;
        Ws[lk + 16][lr] = w1.x; Ws[lk + 17][lr] = w1.y; Ws[lk + 18][lr] = w1.z; Ws[lk + 19][lr] = w1.w;
        __syncthreads();
        #pragma unroll
        for (int kk = 0; kk < 32; ++kk) {
            const float4 a = *reinterpret_cast<const float4*>(&As[kk][r0]);
            const float4 b = *reinterpret_cast<const float4*>(&Ws[kk][c0]);
            acc[0][0] += a.x * b.x; acc[0][1] += a.x * b.y; acc[0][2] += a.x * b.z; acc[0][3] += a.x * b.w;
            acc[1][0] += a.y * b.x; acc[1][1] += a.y * b.y; acc[1][2] += a.y * b.z; acc[1][3] += a.y * b.w;
            acc[2][0] += a.z * b.x; acc[2][1] += a.z * b.y; acc[2][2] += a.z * b.z; acc[2][3] += a.z * b.w;
            acc[3][0] += a.w * b.x; acc[3][1] += a.w * b.y; acc[3][2] += a.w * b.z; acc[3][3] += a.w * b.w;
        }
        __syncthreads();
    }

    float bv[4] = {0.f, 0.f, 0.f, 0.f};
    if (bias) {
        const float4 bb = *reinterpret_cast<const float4*>(&bias[col_tile + c0]);
        bv[0] = bb.x; bv[1] = bb.y; bv[2] = bb.z; bv[3] = bb.w;
    }
    #pragma unroll
    for (int i = 0; i < 4; ++i) {
        long long gr = row_tile + r0 + i;
        if (gr < nrows) {
            float4 o;
            o.x = acc[i][0] + bv[0];
            o.y = acc[i][1] + bv[1];
            o.z = acc[i][2] + bv[2];
            o.w = acc[i][3] + bv[3];
            *reinterpret_cast<float4*>(&C[gr * (long long)ncols + col_tile + c0]) = o;
        }
    }
}

extern "C" void kernel_launch(void* const* d_in, const int* in_sizes, int n_in,
                              void* d_out, int out_size, void* d_ws, size_t ws_size,
                              hipStream_t stream) {
    const float* x     = (const float*)d_in[0];
    const int*   ei    = (const int*)d_in[1];
    const float* W_enc = (const float*)d_in[2];
    const float* b_enc = (const float*)d_in[3];
    const float* W_dec = (const float*)d_in[4];
    const float* b_dec = (const float*)d_in[5];

    const int N = in_sizes[0] / NDIM;       // 100000
    const int E = in_sizes[1] / 2;          // 1600000
    const int* row = ei;        // edge_index[0] = source
    const int* col = ei + E;    // edge_index[1] = target

    const int NPAD = 100352;    // N rounded up to multiple of 256
    float* deg  = (float*)d_ws;
    float* dinv = deg + NPAD;
    float* h    = dinv + NPAD;               // [N][HDIM]
    float* z    = (float*)d_out;             // [N][HDIM]
    float* xrec = (float*)d_out + (size_t)N * HDIM;  // [N][NDIM]

    // 1) degrees (with self-loop)
    k_init_deg<<<(N + 255) / 256, 256, 0, stream>>>(deg, N);
    k_count_deg<<<(E + 255) / 256, 256, 0, stream>>>(col, deg, E);

    // 2) h = x @ W_enc^T
    dim3 g1((N + 63) / 64, HDIM / 64);
    k_gemm_nt<<<g1, 256, 0, stream>>>(x, W_enc, nullptr, h, N, NDIM, HDIM);

    // 3) z_acc = h * dinv^2 (self-loop term), store dinv
    int n32 = N * 32;
    k_selfloop<<<(n32 + 255) / 256, 256, 0, stream>>>(deg, dinv, h, z, N);

    // 4) scatter-add normalized messages
    long long work = (long long)E * 32;
    k_edge_agg<<<(int)((work + 255) / 256), 256, 0, stream>>>(row, col, h, dinv, z, E);

    // 5) z = relu(z + b_enc)
    k_bias_relu<<<(n32 + 255) / 256, 256, 0, stream>>>(z, b_enc, n32);

    // 6) x_recon = z @ W_dec^T + b_dec
    dim3 g2((N + 63) / 64, NDIM / 64);
    k_gemm_nt<<<g2, 256, 0, stream>>>(z, W_dec, b_dec, xrec, N, HDIM, NDIM);
}

// Round 2
// 538.667 us; speedup vs baseline: 5.5468x; 5.5468x over previous
//
#include <hip/hip_runtime.h>
#include <hip/hip_bf16.h>

#define NDIM 256   // IN_DIM
#define HDIM 128   // HID
#define NPAD 100352          // N rounded up to 1024
#define NSCAN (NPAD / 1024)  // 98 scan blocks

// ---------------- degree count (int atomics) ----------------
__global__ __launch_bounds__(256) void k_count_int(const int* __restrict__ col,
                                                   int* __restrict__ cnt, int E) {
    int e = blockIdx.x * 256 + threadIdx.x;
    if (e < E) atomicAdd(&cnt[col[e]], 1);
}

__global__ __launch_bounds__(256) void k_dinv(const int* __restrict__ cnt,
                                              float* __restrict__ dinv, int n) {
    int i = blockIdx.x * 256 + threadIdx.x;
    if (i < n) dinv[i] = rsqrtf((float)(cnt[i] + 1));  // +1 self-loop
}

// ---------------- 3-pass exclusive scan over cnt[NPAD] ----------------
__global__ __launch_bounds__(256) void k_scan1(const int* __restrict__ cnt,
                                               int* __restrict__ bsum) {
    __shared__ int s[256];
    int b = blockIdx.x, t = threadIdx.x;
    const int4 v = *reinterpret_cast<const int4*>(&cnt[b * 1024 + t * 4]);
    s[t] = v.x + v.y + v.z + v.w;
    __syncthreads();
    for (int d = 128; d > 0; d >>= 1) {
        if (t < d) s[t] += s[t + d];
        __syncthreads();
    }
    if (t == 0) bsum[b] = s[0];
}

__global__ __launch_bounds__(128) void k_scan2(const int* __restrict__ bsum,
                                               int* __restrict__ bofs, int nb) {
    __shared__ int s[128];
    int t = threadIdx.x;
    int v = (t < nb) ? bsum[t] : 0;
    s[t] = v;
    __syncthreads();
    for (int d = 1; d < 128; d <<= 1) {
        int x = (t >= d) ? s[t - d] : 0;
        __syncthreads();
        s[t] += x;
        __syncthreads();
    }
    if (t < nb) bofs[t] = s[t] - v;  // exclusive
}

__global__ __launch_bounds__(256) void k_scan3(const int* __restrict__ cnt,
                                               const int* __restrict__ bofs,
                                               int* __restrict__ off) {
    __shared__ int s[256];
    int b = blockIdx.x, t = threadIdx.x;
    const int4 v = *reinterpret_cast<const int4*>(&cnt[b * 1024 + t * 4]);
    int tsum = v.x + v.y + v.z + v.w;
    s[t] = tsum;
    __syncthreads();
    for (int d = 1; d < 256; d <<= 1) {
        int x = (t >= d) ? s[t - d] : 0;
        __syncthreads();
        s[t] += x;
        __syncthreads();
    }
    int excl = s[t] - tsum + bofs[b];
    int4 o;
    o.x = excl; o.y = excl + v.x; o.z = o.y + v.y; o.w = o.z + v.z;
    *reinterpret_cast<int4*>(&off[b * 1024 + t * 4]) = o;
}

// ---------------- bucket fill (CSR by destination) ----------------
__global__ __launch_bounds__(256) void k_fill(const int* __restrict__ row,
                                              const int* __restrict__ col,
                                              const int* __restrict__ off,
                                              int* __restrict__ cur,
                                              int* __restrict__ ebuf, int E) {
    int e = blockIdx.x * 256 + threadIdx.x;
    if (e >= E) return;
    int c = col[e];
    int pos = off[c] + atomicAdd(&cur[c], 1);
    ebuf[pos] = row[e];
}

// ---------------- gather-aggregate + self-loop + bias + relu ----------------
// 128 threads per node (1 feature each), 2 nodes per 256-block.
__global__ __launch_bounds__(256) void k_agg(const int* __restrict__ ebuf,
                                             const int* __restrict__ off,
                                             const int* __restrict__ cnt,
                                             const float* __restrict__ dinv,
                                             const float* __restrict__ h,
                                             const float* __restrict__ benc,
                                             float* __restrict__ z, int n) {
    int node = blockIdx.x * 2 + (threadIdx.x >> 7);
    int f = threadIdx.x & 127;
    if (node >= n) return;
    float dc = dinv[node];
    float acc = h[(size_t)node * HDIM + f] * dc * dc;  // self-loop
    int base = off[node], m = cnt[node];
    int j = 0;
    for (; j + 2 <= m; j += 2) {
        int r0 = ebuf[base + j], r1 = ebuf[base + j + 1];
        float n0 = dinv[r0] * dc, n1 = dinv[r1] * dc;
        acc += h[(size_t)r0 * HDIM + f] * n0;
        acc += h[(size_t)r1 * HDIM + f] * n1;
    }
    if (j < m) {
        int r = ebuf[base + j];
        acc += h[(size_t)r * HDIM + f] * (dinv[r] * dc);
    }
    z[(size_t)node * HDIM + f] = fmaxf(acc + benc[f], 0.f);
}

// ---------------- tiled f32 GEMM:  C[r][c] = sum_k A[r][k]*W[c][k] (+bias[c]) ----------------
__global__ __launch_bounds__(256) void k_gemm_nt(const float* __restrict__ A,
                                                 const float* __restrict__ W,
                                                 const float* __restrict__ bias,
                                                 float* __restrict__ C,
                                                 int nrows, int K, int ncols) {
    __shared__ __align__(16) float As[32][68];
    __shared__ __align__(16) float Ws[32][68];
    const int t = threadIdx.x;
    const long long row_tile = (long long)blockIdx.x * 64;
    const int col_tile = blockIdx.y * 64;
    const int tx = t & 15, ty = t >> 4;
    const int r0 = ty * 4, c0 = tx * 4;
    float acc[4][4] = {};
    const int lr = t >> 2;
    const int lk = (t & 3) * 4;

    for (int k0 = 0; k0 < K; k0 += 32) {
        long long gr = row_tile + lr;
        if (gr >= nrows) gr = nrows - 1;
        const float* asrc = &A[gr * (long long)K + k0 + lk];
        float4 a0 = *reinterpret_cast<const float4*>(asrc);
        float4 a1 = *reinterpret_cast<const float4*>(asrc + 16);
        const float* wsrc = &W[(long long)(col_tile + lr) * K + k0 + lk];
        float4 w0 = *reinterpret_cast<const float4*>(wsrc);
        float4 w1 = *reinterpret_cast<const float4*>(wsrc + 16);
        As[lk + 0][lr] = a0.x; As[lk + 1][lr] = a0.y; As[lk + 2][lr] = a0.z; As[lk + 3][lr] = a0.w;
        As[lk + 16][lr] = a1.x; As[lk + 17][lr] = a1.y; As[lk + 18][lr] = a1.z; As[lk + 19][lr] = a1.w;
        Ws[lk + 0][lr] = w0.x; Ws[lk + 1][lr] = w0.y; Ws[lk + 2][lr] = w0.z; Ws[lk + 3][lr] = w0.w;
        Ws[lk + 16][lr] = w1.x; Ws[lk + 17][lr] = w1.y; Ws[lk + 18][lr] = w1.z; Ws[lk + 19][lr] = w1.w;
        __syncthreads();
        #pragma unroll
        for (int kk = 0; kk < 32; ++kk) {
            const float4 a = *reinterpret_cast<const float4*>(&As[kk][r0]);
            const float4 b = *reinterpret_cast<const float4*>(&Ws[kk][c0]);
            acc[0][0] += a.x * b.x; acc[0][1] += a.x * b.y; acc[0][2] += a.x * b.z; acc[0][3] += a.x * b.w;
            acc[1][0] += a.y * b.x; acc[1][1] += a.y * b.y; acc[1][2] += a.y * b.z; acc[1][3] += a.y * b.w;
            acc[2][0] += a.z * b.x; acc[2][1] += a.z * b.y; acc[2][2] += a.z * b.z; acc[2][3] += a.z * b.w;
            acc[3][0] += a.w * b.x; acc[3][1] += a.w * b.y; acc[3][2] += a.w * b.z; acc[3][3] += a.w * b.w;
        }
        __syncthreads();
    }

    float bv[4] = {0.f, 0.f, 0.f, 0.f};
    if (bias) {
        const float4 bb = *reinterpret_cast<const float4*>(&bias[col_tile + c0]);
        bv[0] = bb.x; bv[1] = bb.y; bv[2] = bb.z; bv[3] = bb.w;
    }
    #pragma unroll
    for (int i = 0; i < 4; ++i) {
        long long gr = row_tile + r0 + i;
        if (gr < nrows) {
            float4 o;
            o.x = acc[i][0] + bv[0];
            o.y = acc[i][1] + bv[1];
            o.z = acc[i][2] + bv[2];
            o.w = acc[i][3] + bv[3];
            *reinterpret_cast<float4*>(&C[gr * (long long)ncols + col_tile + c0]) = o;
        }
    }
}

extern "C" void kernel_launch(void* const* d_in, const int* in_sizes, int n_in,
                              void* d_out, int out_size, void* d_ws, size_t ws_size,
                              hipStream_t stream) {
    const float* x     = (const float*)d_in[0];
    const int*   ei    = (const int*)d_in[1];
    const float* W_enc = (const float*)d_in[2];
    const float* b_enc = (const float*)d_in[3];
    const float* W_dec = (const float*)d_in[4];
    const float* b_dec = (const float*)d_in[5];

    const int N = in_sizes[0] / NDIM;   // 100000
    const int E = in_sizes[1] / 2;      // 1600000
    const int* row = ei;
    const int* col = ei + E;

    // workspace layout
    int*   cnt  = (int*)d_ws;
    int*   cur  = cnt + NPAD;
    int*   off  = cur + NPAD;
    float* dinv = (float*)(off + NPAD);
    int*   bsum = (int*)(dinv + NPAD);
    int*   bofs = bsum + 1024;
    float* h    = (float*)(bofs + 1024);         // [N][HDIM]
    int*   ebuf = (int*)(h + (size_t)N * HDIM);  // [E]

    float* z    = (float*)d_out;
    float* xrec = (float*)d_out + (size_t)N * HDIM;

    hipMemsetAsync(cnt, 0, NPAD * sizeof(int), stream);
    hipMemsetAsync(cur, 0, NPAD * sizeof(int), stream);

    // degree + dinv
    k_count_int<<<(E + 255) / 256, 256, 0, stream>>>(col, cnt, E);
    k_dinv<<<(N + 255) / 256, 256, 0, stream>>>(cnt, dinv, N);

    // exclusive scan -> off
    k_scan1<<<NSCAN, 256, 0, stream>>>(cnt, bsum);
    k_scan2<<<1, 128, 0, stream>>>(bsum, bofs, NSCAN);
    k_scan3<<<NSCAN, 256, 0, stream>>>(cnt, bofs, off);

    // bucket fill
    k_fill<<<(E + 255) / 256, 256, 0, stream>>>(row, col, off, cur, ebuf, E);

    // h = x @ W_enc^T
    dim3 g1((N + 63) / 64, HDIM / 64);
    k_gemm_nt<<<g1, 256, 0, stream>>>(x, W_enc, nullptr, h, N, NDIM, HDIM);

    // z = relu(D^-1/2 A D^-1/2 h + b_enc)   (gather CSR, fused epilogue)
    k_agg<<<(N + 1) / 2, 256, 0, stream>>>(ebuf, off, cnt, dinv, h, b_enc, z, N);

    // x_recon = z @ W_dec^T + b_dec
    dim3 g2((N + 63) / 64, NDIM / 64);
    k_gemm_nt<<<g2, 256, 0, stream>>>(z, W_dec, b_dec, xrec, N, HDIM, NDIM);
}

// Round 3
// 425.698 us; speedup vs baseline: 7.0188x; 1.2654x over previous
//
#include <hip/hip_runtime.h>
#include <hip/hip_bf16.h>

#define NDIM 256   // IN_DIM
#define HDIM 128   // HID
#define NPAD 100352          // N rounded up to 1024
#define NSCAN (NPAD / 1024)  // 98 scan blocks

typedef __bf16 bf16_t;
typedef bf16_t bf16x8 __attribute__((ext_vector_type(8)));
typedef float f32x4 __attribute__((ext_vector_type(4)));

// ---------------- degree count (int atomics) ----------------
__global__ __launch_bounds__(256) void k_count_int(const int* __restrict__ col,
                                                   int* __restrict__ cnt, int E) {
    int e = blockIdx.x * 256 + threadIdx.x;
    if (e < E) atomicAdd(&cnt[col[e]], 1);
}

__global__ __launch_bounds__(256) void k_dinv(const int* __restrict__ cnt,
                                              float* __restrict__ dinv, int n) {
    int i = blockIdx.x * 256 + threadIdx.x;
    if (i < n) dinv[i] = rsqrtf((float)(cnt[i] + 1));  // +1 self-loop
}

// ---------------- weight cast f32 -> bf16 ----------------
__global__ __launch_bounds__(256) void k_castw(const float* __restrict__ src,
                                               bf16_t* __restrict__ dst, int n) {
    int i = blockIdx.x * 256 + threadIdx.x;
    if (i < n) dst[i] = (bf16_t)src[i];
}

// ---------------- 3-pass exclusive scan over cnt[NPAD] ----------------
__global__ __launch_bounds__(256) void k_scan1(const int* __restrict__ cnt,
                                               int* __restrict__ bsum) {
    __shared__ int s[256];
    int b = blockIdx.x, t = threadIdx.x;
    const int4 v = *reinterpret_cast<const int4*>(&cnt[b * 1024 + t * 4]);
    s[t] = v.x + v.y + v.z + v.w;
    __syncthreads();
    for (int d = 128; d > 0; d >>= 1) {
        if (t < d) s[t] += s[t + d];
        __syncthreads();
    }
    if (t == 0) bsum[b] = s[0];
}

__global__ __launch_bounds__(128) void k_scan2(const int* __restrict__ bsum,
                                               int* __restrict__ bofs, int nb) {
    __shared__ int s[128];
    int t = threadIdx.x;
    int v = (t < nb) ? bsum[t] : 0;
    s[t] = v;
    __syncthreads();
    for (int d = 1; d < 128; d <<= 1) {
        int x = (t >= d) ? s[t - d] : 0;
        __syncthreads();
        s[t] += x;
        __syncthreads();
    }
    if (t < nb) bofs[t] = s[t] - v;  // exclusive
}

__global__ __launch_bounds__(256) void k_scan3(const int* __restrict__ cnt,
                                               const int* __restrict__ bofs,
                                               int* __restrict__ off) {
    __shared__ int s[256];
    int b = blockIdx.x, t = threadIdx.x;
    const int4 v = *reinterpret_cast<const int4*>(&cnt[b * 1024 + t * 4]);
    int tsum = v.x + v.y + v.z + v.w;
    s[t] = tsum;
    __syncthreads();
    for (int d = 1; d < 256; d <<= 1) {
        int x = (t >= d) ? s[t - d] : 0;
        __syncthreads();
        s[t] += x;
        __syncthreads();
    }
    int excl = s[t] - tsum + bofs[b];
    int4 o;
    o.x = excl; o.y = excl + v.x; o.z = o.y + v.y; o.w = o.z + v.z;
    *reinterpret_cast<int4*>(&off[b * 1024 + t * 4]) = o;
}

// ---------------- bucket fill (CSR by destination) ----------------
__global__ __launch_bounds__(256) void k_fill(const int* __restrict__ row,
                                              const int* __restrict__ col,
                                              const int* __restrict__ off,
                                              int* __restrict__ cur,
                                              int* __restrict__ ebuf, int E) {
    int e = blockIdx.x * 256 + threadIdx.x;
    if (e >= E) return;
    int c = col[e];
    int pos = off[c] + atomicAdd(&cur[c], 1);
    ebuf[pos] = row[e];
}

// ---------------- MFMA GEMM: C[r][c] = sum_k A[r][k] * W[c][k] (+bias) ----------------
// A: f32 [nrows][K] (inline cvt to bf16); W: bf16 [NC][K]; 256 thr = 4 waves,
// 64 rows/block (16/wave), full NC width per wave.
// mfma_f32_16x16x32_bf16 layouts: A lane l -> row l&15, k = (l>>4)*8+j;
// B lane l -> col l&15, k = (l>>4)*8+j; C/D lane l reg i -> col l&15, row (l>>4)*4+i. [m89]
template<int K, int NC, bool OUT_BF16>
__global__ __launch_bounds__(256) void k_gemm_mfma(const float* __restrict__ A,
                                                   const bf16_t* __restrict__ W,
                                                   const float* __restrict__ bias,
                                                   void* __restrict__ Cout,
                                                   int nrows) {
    const int lane = threadIdx.x & 63;
    const int wv = threadIdx.x >> 6;     // 0..3
    const int fr = lane & 15;            // fragment row (A) / col (B,C)
    const int kg = lane >> 4;            // k-group 0..3
    constexpr int NF = NC / 16;

    long long arow = (long long)blockIdx.x * 64 + wv * 16 + fr;
    if (arow >= nrows) arow = nrows - 1;
    const float* abase = A + arow * K + kg * 8;

    f32x4 acc[NF];
    const f32x4 zero4 = {0.f, 0.f, 0.f, 0.f};
    #pragma unroll
    for (int nf = 0; nf < NF; ++nf) acc[nf] = zero4;

    #pragma unroll
    for (int kk = 0; kk < K; kk += 32) {
        const f32x4 a0 = *reinterpret_cast<const f32x4*>(abase + kk);
        const f32x4 a1 = *reinterpret_cast<const f32x4*>(abase + kk + 4);
        bf16x8 af;
        af[0] = (bf16_t)a0[0]; af[1] = (bf16_t)a0[1]; af[2] = (bf16_t)a0[2]; af[3] = (bf16_t)a0[3];
        af[4] = (bf16_t)a1[0]; af[5] = (bf16_t)a1[1]; af[6] = (bf16_t)a1[2]; af[7] = (bf16_t)a1[3];
        #pragma unroll
        for (int nf = 0; nf < NF; ++nf) {
            const bf16x8 bf = *reinterpret_cast<const bf16x8*>(&W[(size_t)(nf * 16 + fr) * K + kk + kg * 8]);
            acc[nf] = __builtin_amdgcn_mfma_f32_16x16x32_bf16(af, bf, acc[nf], 0, 0, 0);
        }
    }

    const long long rbase = (long long)blockIdx.x * 64 + wv * 16 + kg * 4;
    #pragma unroll
    for (int nf = 0; nf < NF; ++nf) {
        const int c = nf * 16 + fr;
        const float bv = bias ? bias[c] : 0.f;
        #pragma unroll
        for (int i = 0; i < 4; ++i) {
            const long long r = rbase + i;
            if (r < nrows) {
                const float v = acc[nf][i] + bv;
                if (OUT_BF16) {
                    ((bf16_t*)Cout)[r * NC + c] = (bf16_t)v;
                } else {
                    ((float*)Cout)[r * NC + c] = v;
                }
            }
        }
    }
}

// ---------------- gather-aggregate + self-loop + bias + relu ----------------
// 1 wave per node; lane handles 2 features (uint load of 2 bf16).
__device__ __forceinline__ float bflo(unsigned u) { return __uint_as_float(u << 16); }
__device__ __forceinline__ float bfhi(unsigned u) { return __uint_as_float(u & 0xffff0000u); }

__global__ __launch_bounds__(256) void k_agg(const int* __restrict__ ebuf,
                                             const int* __restrict__ off,
                                             const int* __restrict__ cnt,
                                             const float* __restrict__ dinv,
                                             const unsigned* __restrict__ hb,  // bf16 pairs [N][64]
                                             const float* __restrict__ benc,
                                             float* __restrict__ z, int n) {
    const int node = blockIdx.x * 4 + (threadIdx.x >> 6);
    const int lane = threadIdx.x & 63;
    if (node >= n) return;
    const float dc = dinv[node];
    const unsigned hself = hb[(size_t)node * 64 + lane];
    float acc0 = bflo(hself) * (dc * dc);
    float acc1 = bfhi(hself) * (dc * dc);
    const int base = off[node], m = cnt[node];
    int j = 0;
    for (; j + 2 <= m; j += 2) {
        const int r0 = ebuf[base + j], r1 = ebuf[base + j + 1];
        const float n0 = dinv[r0] * dc, n1 = dinv[r1] * dc;
        const unsigned u0 = hb[(size_t)r0 * 64 + lane];
        const unsigned u1 = hb[(size_t)r1 * 64 + lane];
        acc0 += bflo(u0) * n0;
        acc1 += bfhi(u0) * n0;
        acc0 += bflo(u1) * n1;
        acc1 += bfhi(u1) * n1;
    }
    if (j < m) {
        const int r = ebuf[base + j];
        const float nr = dinv[r] * dc;
        const unsigned u = hb[(size_t)r * 64 + lane];
        acc0 += bflo(u) * nr;
        acc1 += bfhi(u) * nr;
    }
    float2 o;
    o.x = fmaxf(acc0 + benc[lane * 2], 0.f);
    o.y = fmaxf(acc1 + benc[lane * 2 + 1], 0.f);
    *reinterpret_cast<float2*>(&z[(size_t)node * HDIM + lane * 2]) = o;
}

extern "C" void kernel_launch(void* const* d_in, const int* in_sizes, int n_in,
                              void* d_out, int out_size, void* d_ws, size_t ws_size,
                              hipStream_t stream) {
    const float* x     = (const float*)d_in[0];
    const int*   ei    = (const int*)d_in[1];
    const float* W_enc = (const float*)d_in[2];
    const float* b_enc = (const float*)d_in[3];
    const float* W_dec = (const float*)d_in[4];
    const float* b_dec = (const float*)d_in[5];

    const int N = in_sizes[0] / NDIM;   // 100000
    const int E = in_sizes[1] / 2;      // 1600000
    const int* row = ei;
    const int* col = ei + E;

    // workspace layout
    int*    cnt   = (int*)d_ws;
    int*    cur   = cnt + NPAD;
    int*    off   = cur + NPAD;
    float*  dinv  = (float*)(off + NPAD);
    int*    bsum  = (int*)(dinv + NPAD);
    int*    bofs  = bsum + 1024;
    bf16_t* wbe   = (bf16_t*)(bofs + 1024);              // [HDIM][NDIM]
    bf16_t* wbd   = wbe + HDIM * NDIM;                   // [NDIM][HDIM]
    bf16_t* hb    = wbd + NDIM * HDIM;                   // [N][HDIM] bf16
    int*    ebuf  = (int*)(hb + (size_t)N * HDIM);       // [E]

    float* z    = (float*)d_out;
    float* xrec = (float*)d_out + (size_t)N * HDIM;

    hipMemsetAsync(cnt, 0, NPAD * sizeof(int), stream);
    hipMemsetAsync(cur, 0, NPAD * sizeof(int), stream);

    // degree + dinv
    k_count_int<<<(E + 255) / 256, 256, 0, stream>>>(col, cnt, E);
    k_dinv<<<(N + 255) / 256, 256, 0, stream>>>(cnt, dinv, N);

    // weight casts
    k_castw<<<(HDIM * NDIM + 255) / 256, 256, 0, stream>>>(W_enc, wbe, HDIM * NDIM);
    k_castw<<<(NDIM * HDIM + 255) / 256, 256, 0, stream>>>(W_dec, wbd, NDIM * HDIM);

    // exclusive scan -> off
    k_scan1<<<NSCAN, 256, 0, stream>>>(cnt, bsum);
    k_scan2<<<1, 128, 0, stream>>>(bsum, bofs, NSCAN);
    k_scan3<<<NSCAN, 256, 0, stream>>>(cnt, bofs, off);

    // bucket fill
    k_fill<<<(E + 255) / 256, 256, 0, stream>>>(row, col, off, cur, ebuf, E);

    // h_bf16 = bf16(x @ W_enc^T)
    k_gemm_mfma<NDIM, HDIM, true><<<(N + 63) / 64, 256, 0, stream>>>(x, wbe, nullptr, hb, N);

    // z = relu(D^-1/2 A D^-1/2 h + b_enc)
    k_agg<<<(N + 3) / 4, 256, 0, stream>>>(ebuf, off, cnt, dinv, (const unsigned*)hb, b_enc, z, N);

    // x_recon = z @ W_dec^T + b_dec
    k_gemm_mfma<HDIM, NDIM, false><<<(N + 63) / 64, 256, 0, stream>>>(z, wbd, b_dec, xrec, N);
}

// Round 4
// 393.094 us; speedup vs baseline: 7.6010x; 1.0829x over previous
//
#include <hip/hip_runtime.h>
#include <hip/hip_bf16.h>

#define NDIM 256   // IN_DIM
#define HDIM 128   // HID
#define NPAD 100352          // N rounded up to 1024
#define NSCAN (NPAD / 1024)  // 98 scan blocks

typedef __bf16 bf16_t;
typedef bf16_t bf16x8 __attribute__((ext_vector_type(8)));
typedef float f32x4 __attribute__((ext_vector_type(4)));

// ---------------- degree count (int atomics) ----------------
__global__ __launch_bounds__(256) void k_count_int(const int* __restrict__ col,
                                                   int* __restrict__ cnt, int E) {
    int e = blockIdx.x * 256 + threadIdx.x;
    if (e < E) atomicAdd(&cnt[col[e]], 1);
}

// ---------------- weight cast f32 -> bf16 (both weights, one dispatch) ----------------
__global__ __launch_bounds__(256) void k_castw2(const float* __restrict__ s1, bf16_t* __restrict__ d1, int n1,
                                                const float* __restrict__ s2, bf16_t* __restrict__ d2, int n2) {
    int i = blockIdx.x * 256 + threadIdx.x;
    if (i < n1) d1[i] = (bf16_t)s1[i];
    else if (i < n1 + n2) d2[i - n1] = (bf16_t)s2[i - n1];
}

// ---------------- scan pass 1 (+ fused dinv) ----------------
__global__ __launch_bounds__(256) void k_scan1(const int* __restrict__ cnt,
                                               int* __restrict__ bsum,
                                               float* __restrict__ dinv) {
    __shared__ int s[256];
    int b = blockIdx.x, t = threadIdx.x;
    const int4 v = *reinterpret_cast<const int4*>(&cnt[b * 1024 + t * 4]);
    float4 dv;
    dv.x = rsqrtf((float)(v.x + 1));
    dv.y = rsqrtf((float)(v.y + 1));
    dv.z = rsqrtf((float)(v.z + 1));
    dv.w = rsqrtf((float)(v.w + 1));
    *reinterpret_cast<float4*>(&dinv[b * 1024 + t * 4]) = dv;
    s[t] = v.x + v.y + v.z + v.w;
    __syncthreads();
    for (int d = 128; d > 0; d >>= 1) {
        if (t < d) s[t] += s[t + d];
        __syncthreads();
    }
    if (t == 0) bsum[b] = s[0];
}

__global__ __launch_bounds__(128) void k_scan2(const int* __restrict__ bsum,
                                               int* __restrict__ bofs, int nb) {
    __shared__ int s[128];
    int t = threadIdx.x;
    int v = (t < nb) ? bsum[t] : 0;
    s[t] = v;
    __syncthreads();
    for (int d = 1; d < 128; d <<= 1) {
        int x = (t >= d) ? s[t - d] : 0;
        __syncthreads();
        s[t] += x;
        __syncthreads();
    }
    if (t < nb) bofs[t] = s[t] - v;  // exclusive
}

__global__ __launch_bounds__(256) void k_scan3(const int* __restrict__ cnt,
                                               const int* __restrict__ bofs,
                                               int* __restrict__ off) {
    __shared__ int s[256];
    int b = blockIdx.x, t = threadIdx.x;
    const int4 v = *reinterpret_cast<const int4*>(&cnt[b * 1024 + t * 4]);
    int tsum = v.x + v.y + v.z + v.w;
    s[t] = tsum;
    __syncthreads();
    for (int d = 1; d < 256; d <<= 1) {
        int x = (t >= d) ? s[t - d] : 0;
        __syncthreads();
        s[t] += x;
        __syncthreads();
    }
    int excl = s[t] - tsum + bofs[b];
    int4 o;
    o.x = excl; o.y = excl + v.x; o.z = o.y + v.y; o.w = o.z + v.z;
    *reinterpret_cast<int4*>(&off[b * 1024 + t * 4]) = o;
}

// ---------------- bucket fill (CSR by destination) ----------------
__global__ __launch_bounds__(256) void k_fill(const int* __restrict__ row,
                                              const int* __restrict__ col,
                                              const int* __restrict__ off,
                                              int* __restrict__ cur,
                                              int* __restrict__ ebuf, int E) {
    int e = blockIdx.x * 256 + threadIdx.x;
    if (e >= E) return;
    int c = col[e];
    int pos = off[c] + atomicAdd(&cur[c], 1);
    ebuf[pos] = row[e];
}

// ---------------- MFMA GEMM: C[r][c] = sum_k A[r][k] * W[c][k] (+bias) ----------------
// A: f32 (inline cvt to bf16); W: bf16 [NC][K]. 4 waves/block, RW 16-row
// fragments per wave (B-fragment reused across RW).
// mfma_f32_16x16x32_bf16: A lane l -> row l&15, k=(l>>4)*8+j; B lane l -> col l&15,
// same k; C/D lane l reg i -> col l&15, row (l>>4)*4+i. [m89]
template<int K, int NC, int RW, bool OUT_BF16>
__global__ __launch_bounds__(256) void k_gemm_mfma(const float* __restrict__ A,
                                                   const bf16_t* __restrict__ W,
                                                   const float* __restrict__ bias,
                                                   void* __restrict__ Cout,
                                                   int nrows) {
    const int lane = threadIdx.x & 63;
    const int wv = threadIdx.x >> 6;     // 0..3
    const int fr = lane & 15;
    const int kg = lane >> 4;            // 0..3
    constexpr int NF = NC / 16;
    const long long wrow = (long long)blockIdx.x * (RW * 64) + wv * (RW * 16);

    const float* abase[RW];
    #pragma unroll
    for (int rf = 0; rf < RW; ++rf) {
        long long ar = wrow + rf * 16 + fr;
        if (ar >= nrows) ar = nrows - 1;
        abase[rf] = A + ar * K + kg * 8;
    }

    f32x4 acc[RW][NF];
    const f32x4 zero4 = {0.f, 0.f, 0.f, 0.f};
    #pragma unroll
    for (int rf = 0; rf < RW; ++rf)
        #pragma unroll
        for (int nf = 0; nf < NF; ++nf) acc[rf][nf] = zero4;

    #pragma unroll
    for (int kk = 0; kk < K; kk += 32) {
        bf16x8 af[RW];
        #pragma unroll
        for (int rf = 0; rf < RW; ++rf) {
            const f32x4 a0 = *reinterpret_cast<const f32x4*>(abase[rf] + kk);
            const f32x4 a1 = *reinterpret_cast<const f32x4*>(abase[rf] + kk + 4);
            af[rf][0] = (bf16_t)a0[0]; af[rf][1] = (bf16_t)a0[1];
            af[rf][2] = (bf16_t)a0[2]; af[rf][3] = (bf16_t)a0[3];
            af[rf][4] = (bf16_t)a1[0]; af[rf][5] = (bf16_t)a1[1];
            af[rf][6] = (bf16_t)a1[2]; af[rf][7] = (bf16_t)a1[3];
        }
        #pragma unroll
        for (int nf = 0; nf < NF; ++nf) {
            const bf16x8 bf = *reinterpret_cast<const bf16x8*>(&W[(size_t)(nf * 16 + fr) * K + kk + kg * 8]);
            #pragma unroll
            for (int rf = 0; rf < RW; ++rf)
                acc[rf][nf] = __builtin_amdgcn_mfma_f32_16x16x32_bf16(af[rf], bf, acc[rf][nf], 0, 0, 0);
        }
    }

    #pragma unroll
    for (int rf = 0; rf < RW; ++rf) {
        const long long rbase = wrow + rf * 16 + kg * 4;
        #pragma unroll
        for (int nf = 0; nf < NF; ++nf) {
            const int c = nf * 16 + fr;
            const float bv = bias ? bias[c] : 0.f;
            #pragma unroll
            for (int i = 0; i < 4; ++i) {
                const long long r = rbase + i;
                if (r < nrows) {
                    const float v = acc[rf][nf][i] + bv;
                    if (OUT_BF16) {
                        ((bf16_t*)Cout)[r * NC + c] = (bf16_t)v;
                    } else {
                        ((float*)Cout)[r * NC + c] = v;
                    }
                }
            }
        }
    }
}

// ---------------- gather-aggregate + self-loop + bias + relu ----------------
// 1 wave per node; lane handles 2 features (uint = 2 bf16); 4-deep MLP unroll.
__device__ __forceinline__ float bflo(unsigned u) { return __uint_as_float(u << 16); }
__device__ __forceinline__ float bfhi(unsigned u) { return __uint_as_float(u & 0xffff0000u); }

__global__ __launch_bounds__(256) void k_agg(const int* __restrict__ ebuf,
                                             const int* __restrict__ off,
                                             const int* __restrict__ cnt,
                                             const float* __restrict__ dinv,
                                             const unsigned* __restrict__ hb,  // bf16 pairs [N][64]
                                             const float* __restrict__ benc,
                                             float* __restrict__ z, int n) {
    const int node = blockIdx.x * 4 + (threadIdx.x >> 6);
    const int lane = threadIdx.x & 63;
    if (node >= n) return;
    const float dc = dinv[node];
    const unsigned hself = hb[(size_t)node * 64 + lane];
    float acc0 = bflo(hself) * (dc * dc);
    float acc1 = bfhi(hself) * (dc * dc);
    const int base = off[node], m = cnt[node];
    int j = 0;
    for (; j + 4 <= m; j += 4) {
        const int r0 = ebuf[base + j];
        const int r1 = ebuf[base + j + 1];
        const int r2 = ebuf[base + j + 2];
        const int r3 = ebuf[base + j + 3];
        const float d0 = dinv[r0], d1 = dinv[r1], d2 = dinv[r2], d3 = dinv[r3];
        const unsigned u0 = hb[(size_t)r0 * 64 + lane];
        const unsigned u1 = hb[(size_t)r1 * 64 + lane];
        const unsigned u2 = hb[(size_t)r2 * 64 + lane];
        const unsigned u3 = hb[(size_t)r3 * 64 + lane];
        const float n0 = d0 * dc, n1 = d1 * dc, n2 = d2 * dc, n3 = d3 * dc;
        acc0 += bflo(u0) * n0; acc1 += bfhi(u0) * n0;
        acc0 += bflo(u1) * n1; acc1 += bfhi(u1) * n1;
        acc0 += bflo(u2) * n2; acc1 += bfhi(u2) * n2;
        acc0 += bflo(u3) * n3; acc1 += bfhi(u3) * n3;
    }
    for (; j < m; ++j) {
        const int r = ebuf[base + j];
        const float nr = dinv[r] * dc;
        const unsigned u = hb[(size_t)r * 64 + lane];
        acc0 += bflo(u) * nr;
        acc1 += bfhi(u) * nr;
    }
    float2 o;
    o.x = fmaxf(acc0 + benc[lane * 2], 0.f);
    o.y = fmaxf(acc1 + benc[lane * 2 + 1], 0.f);
    *reinterpret_cast<float2*>(&z[(size_t)node * HDIM + lane * 2]) = o;
}

extern "C" void kernel_launch(void* const* d_in, const int* in_sizes, int n_in,
                              void* d_out, int out_size, void* d_ws, size_t ws_size,
                              hipStream_t stream) {
    const float* x     = (const float*)d_in[0];
    const int*   ei    = (const int*)d_in[1];
    const float* W_enc = (const float*)d_in[2];
    const float* b_enc = (const float*)d_in[3];
    const float* W_dec = (const float*)d_in[4];
    const float* b_dec = (const float*)d_in[5];

    const int N = in_sizes[0] / NDIM;   // 100000
    const int E = in_sizes[1] / 2;      // 1600000
    const int* row = ei;
    const int* col = ei + E;

    // workspace layout (cnt and cur adjacent -> single memset)
    int*    cnt   = (int*)d_ws;
    int*    cur   = cnt + NPAD;
    int*    off   = cur + NPAD;
    float*  dinv  = (float*)(off + NPAD);
    int*    bsum  = (int*)(dinv + NPAD);
    int*    bofs  = bsum + 1024;
    bf16_t* wbe   = (bf16_t*)(bofs + 1024);              // [HDIM][NDIM]
    bf16_t* wbd   = wbe + HDIM * NDIM;                   // [NDIM][HDIM]
    bf16_t* hb    = wbd + NDIM * HDIM;                   // [N][HDIM] bf16
    int*    ebuf  = (int*)(hb + (size_t)N * HDIM);       // [E]

    float* z    = (float*)d_out;
    float* xrec = (float*)d_out + (size_t)N * HDIM;

    hipMemsetAsync(cnt, 0, 2 * NPAD * sizeof(int), stream);

    // degree
    k_count_int<<<(E + 255) / 256, 256, 0, stream>>>(col, cnt, E);

    // exclusive scan -> off (pass1 also emits dinv)
    k_scan1<<<NSCAN, 256, 0, stream>>>(cnt, bsum, dinv);
    k_scan2<<<1, 128, 0, stream>>>(bsum, bofs, NSCAN);
    k_scan3<<<NSCAN, 256, 0, stream>>>(cnt, bofs, off);

    // bucket fill
    k_fill<<<(E + 255) / 256, 256, 0, stream>>>(row, col, off, cur, ebuf, E);

    // weight casts (single dispatch)
    k_castw2<<<(HDIM * NDIM + NDIM * HDIM + 255) / 256, 256, 0, stream>>>(
        W_enc, wbe, HDIM * NDIM, W_dec, wbd, NDIM * HDIM);

    // h_bf16 = bf16(x @ W_enc^T)   (32 rows/wave, 128 rows/block)
    k_gemm_mfma<NDIM, HDIM, 2, true><<<(N + 127) / 128, 256, 0, stream>>>(x, wbe, nullptr, hb, N);

    // z = relu(D^-1/2 A D^-1/2 h + b_enc)
    k_agg<<<(N + 3) / 4, 256, 0, stream>>>(ebuf, off, cnt, dinv, (const unsigned*)hb, b_enc, z, N);

    // x_recon = z @ W_dec^T + b_dec   (16 rows/wave)
    k_gemm_mfma<HDIM, NDIM, 1, false><<<(N + 63) / 64, 256, 0, stream>>>(z, wbd, b_dec, xrec, N);
}

// Round 5
// 347.061 us; speedup vs baseline: 8.6091x; 1.1326x over previous
//
#include <hip/hip_runtime.h>
#include <hip/hip_bf16.h>

#define NDIM 256   // IN_DIM
#define HDIM 128   // HID
#define NPAD 100352          // N rounded up to 1024
#define NSCAN (NPAD / 1024)  // 98 scan blocks
#define CASTBLKS 64          // 16384 float4 of weights / 256 thr

typedef __bf16 bf16_t;
typedef bf16_t bf16x4 __attribute__((ext_vector_type(4)));
typedef bf16_t bf16x8 __attribute__((ext_vector_type(8)));
typedef float f32x4 __attribute__((ext_vector_type(4)));

// ---------------- pass A: count + per-edge rank (atomic w/ return, 4 edges/thread) ----------------
__global__ __launch_bounds__(256) void k_count_rank(const int* __restrict__ col,
                                                    int* __restrict__ cnt,
                                                    int* __restrict__ rank, int E) {
    const int idx = blockIdx.x * 256 + threadIdx.x;
    const int e0 = idx * 4;
    if (e0 >= E) return;
    if (e0 + 4 <= E) {
        const int4 c = *reinterpret_cast<const int4*>(&col[e0]);
        int4 r;
        r.x = atomicAdd(&cnt[c.x], 1);
        r.y = atomicAdd(&cnt[c.y], 1);
        r.z = atomicAdd(&cnt[c.z], 1);
        r.w = atomicAdd(&cnt[c.w], 1);
        *reinterpret_cast<int4*>(&rank[e0]) = r;
    } else {
        for (int e = e0; e < E; ++e) rank[e] = atomicAdd(&cnt[col[e]], 1);
    }
}

// ---------------- scan pass 1 (+ fused dinv + fused weight casts) ----------------
__global__ __launch_bounds__(256) void k_scan1(const int* __restrict__ cnt,
                                               int* __restrict__ bsum,
                                               float* __restrict__ dinv,
                                               const float* __restrict__ We, bf16_t* __restrict__ wbe,
                                               const float* __restrict__ Wd, bf16_t* __restrict__ wbd) {
    const int b = blockIdx.x, t = threadIdx.x;
    if (b >= NSCAN) {
        // weight cast: chunk index over concat(W_enc, W_dec) as float4
        const int i = (b - NSCAN) * 256 + t;  // 0..16383
        const bool enc = i < 8192;
        const float4 v = *reinterpret_cast<const float4*>(enc ? &We[i * 4] : &Wd[(i - 8192) * 4]);
        bf16x4 o;
        o[0] = (bf16_t)v.x; o[1] = (bf16_t)v.y; o[2] = (bf16_t)v.z; o[3] = (bf16_t)v.w;
        *reinterpret_cast<bf16x4*>(enc ? &wbe[i * 4] : &wbd[(i - 8192) * 4]) = o;
        return;
    }
    __shared__ int s[256];
    const int4 v = *reinterpret_cast<const int4*>(&cnt[b * 1024 + t * 4]);
    float4 dv;
    dv.x = rsqrtf((float)(v.x + 1));
    dv.y = rsqrtf((float)(v.y + 1));
    dv.z = rsqrtf((float)(v.z + 1));
    dv.w = rsqrtf((float)(v.w + 1));
    *reinterpret_cast<float4*>(&dinv[b * 1024 + t * 4]) = dv;
    s[t] = v.x + v.y + v.z + v.w;
    __syncthreads();
    for (int d = 128; d > 0; d >>= 1) {
        if (t < d) s[t] += s[t + d];
        __syncthreads();
    }
    if (t == 0) bsum[b] = s[0];
}

__global__ __launch_bounds__(128) void k_scan2(const int* __restrict__ bsum,
                                               int* __restrict__ bofs, int nb) {
    __shared__ int s[128];
    int t = threadIdx.x;
    int v = (t < nb) ? bsum[t] : 0;
    s[t] = v;
    __syncthreads();
    for (int d = 1; d < 128; d <<= 1) {
        int x = (t >= d) ? s[t - d] : 0;
        __syncthreads();
        s[t] += x;
        __syncthreads();
    }
    if (t < nb) bofs[t] = s[t] - v;  // exclusive
}

__global__ __launch_bounds__(256) void k_scan3(const int* __restrict__ cnt,
                                               const int* __restrict__ bofs,
                                               int* __restrict__ off) {
    __shared__ int s[256];
    int b = blockIdx.x, t = threadIdx.x;
    const int4 v = *reinterpret_cast<const int4*>(&cnt[b * 1024 + t * 4]);
    int tsum = v.x + v.y + v.z + v.w;
    s[t] = tsum;
    __syncthreads();
    for (int d = 1; d < 256; d <<= 1) {
        int x = (t >= d) ? s[t - d] : 0;
        __syncthreads();
        s[t] += x;
        __syncthreads();
    }
    int excl = s[t] - tsum + bofs[b];
    int4 o;
    o.x = excl; o.y = excl + v.x; o.z = o.y + v.y; o.w = o.z + v.z;
    *reinterpret_cast<int4*>(&off[b * 1024 + t * 4]) = o;
}

// ---------------- pass B: atomic-free scatter (4 edges/thread) ----------------
__global__ __launch_bounds__(256) void k_scatter(const int* __restrict__ row,
                                                 const int* __restrict__ col,
                                                 const int* __restrict__ rank,
                                                 const int* __restrict__ off,
                                                 int* __restrict__ ebuf, int E) {
    const int idx = blockIdx.x * 256 + threadIdx.x;
    const int e0 = idx * 4;
    if (e0 >= E) return;
    if (e0 + 4 <= E) {
        const int4 c = *reinterpret_cast<const int4*>(&col[e0]);
        const int4 r = *reinterpret_cast<const int4*>(&row[e0]);
        const int4 k = *reinterpret_cast<const int4*>(&rank[e0]);
        const int o0 = off[c.x], o1 = off[c.y], o2 = off[c.z], o3 = off[c.w];
        ebuf[o0 + k.x] = r.x;
        ebuf[o1 + k.y] = r.y;
        ebuf[o2 + k.z] = r.z;
        ebuf[o3 + k.w] = r.w;
    } else {
        for (int e = e0; e < E; ++e) ebuf[off[col[e]] + rank[e]] = row[e];
    }
}

// ---------------- MFMA GEMM: C[r][c] = sum_k A[r][k] * W[c][k] (+bias) ----------------
// A: f32 (inline cvt to bf16); W: bf16 [NC][K]. 4 waves/block, RW 16-row
// fragments per wave. mfma_f32_16x16x32_bf16: A lane l -> row l&15, k=(l>>4)*8+j;
// B lane l -> col l&15, same k; C/D lane l reg i -> col l&15, row (l>>4)*4+i. [m89]
template<int K, int NC, int RW, bool OUT_BF16>
__global__ __launch_bounds__(256) void k_gemm_mfma(const float* __restrict__ A,
                                                   const bf16_t* __restrict__ W,
                                                   const float* __restrict__ bias,
                                                   void* __restrict__ Cout,
                                                   int nrows) {
    const int lane = threadIdx.x & 63;
    const int wv = threadIdx.x >> 6;     // 0..3
    const int fr = lane & 15;
    const int kg = lane >> 4;            // 0..3
    constexpr int NF = NC / 16;
    const long long wrow = (long long)blockIdx.x * (RW * 64) + wv * (RW * 16);

    const float* abase[RW];
    #pragma unroll
    for (int rf = 0; rf < RW; ++rf) {
        long long ar = wrow + rf * 16 + fr;
        if (ar >= nrows) ar = nrows - 1;
        abase[rf] = A + ar * K + kg * 8;
    }

    f32x4 acc[RW][NF];
    const f32x4 zero4 = {0.f, 0.f, 0.f, 0.f};
    #pragma unroll
    for (int rf = 0; rf < RW; ++rf)
        #pragma unroll
        for (int nf = 0; nf < NF; ++nf) acc[rf][nf] = zero4;

    #pragma unroll
    for (int kk = 0; kk < K; kk += 32) {
        bf16x8 af[RW];
        #pragma unroll
        for (int rf = 0; rf < RW; ++rf) {
            const f32x4 a0 = *reinterpret_cast<const f32x4*>(abase[rf] + kk);
            const f32x4 a1 = *reinterpret_cast<const f32x4*>(abase[rf] + kk + 4);
            af[rf][0] = (bf16_t)a0[0]; af[rf][1] = (bf16_t)a0[1];
            af[rf][2] = (bf16_t)a0[2]; af[rf][3] = (bf16_t)a0[3];
            af[rf][4] = (bf16_t)a1[0]; af[rf][5] = (bf16_t)a1[1];
            af[rf][6] = (bf16_t)a1[2]; af[rf][7] = (bf16_t)a1[3];
        }
        #pragma unroll
        for (int nf = 0; nf < NF; ++nf) {
            const bf16x8 bf = *reinterpret_cast<const bf16x8*>(&W[(size_t)(nf * 16 + fr) * K + kk + kg * 8]);
            #pragma unroll
            for (int rf = 0; rf < RW; ++rf)
                acc[rf][nf] = __builtin_amdgcn_mfma_f32_16x16x32_bf16(af[rf], bf, acc[rf][nf], 0, 0, 0);
        }
    }

    #pragma unroll
    for (int rf = 0; rf < RW; ++rf) {
        const long long rbase = wrow + rf * 16 + kg * 4;
        #pragma unroll
        for (int nf = 0; nf < NF; ++nf) {
            const int c = nf * 16 + fr;
            const float bv = bias ? bias[c] : 0.f;
            #pragma unroll
            for (int i = 0; i < 4; ++i) {
                const long long r = rbase + i;
                if (r < nrows) {
                    const float v = acc[rf][nf][i] + bv;
                    if (OUT_BF16) {
                        ((bf16_t*)Cout)[r * NC + c] = (bf16_t)v;
                    } else {
                        ((float*)Cout)[r * NC + c] = v;
                    }
                }
            }
        }
    }
}

// ---------------- gather-aggregate + self-loop + bias + relu ----------------
// 1 wave per node; lane = 2 features (uint = 2 bf16); 8-deep gather unroll.
__device__ __forceinline__ float bflo(unsigned u) { return __uint_as_float(u << 16); }
__device__ __forceinline__ float bfhi(unsigned u) { return __uint_as_float(u & 0xffff0000u); }

__global__ __launch_bounds__(256) void k_agg(const int* __restrict__ ebuf,
                                             const int* __restrict__ off,
                                             const int* __restrict__ cnt,
                                             const float* __restrict__ dinv,
                                             const unsigned* __restrict__ hb,  // bf16 pairs [N][64]
                                             const float* __restrict__ benc,
                                             float* __restrict__ z, int n) {
    const int node = blockIdx.x * 4 + (threadIdx.x >> 6);
    const int lane = threadIdx.x & 63;
    if (node >= n) return;
    const float dc = dinv[node];
    const unsigned hself = hb[(size_t)node * 64 + lane];
    float acc0 = bflo(hself) * (dc * dc);
    float acc1 = bfhi(hself) * (dc * dc);
    const int base = off[node], m = cnt[node];
    int j = 0;
    for (; j + 8 <= m; j += 8) {
        int r[8]; float d[8]; unsigned u[8];
        #pragma unroll
        for (int q = 0; q < 8; ++q) r[q] = ebuf[base + j + q];
        #pragma unroll
        for (int q = 0; q < 8; ++q) d[q] = dinv[r[q]];
        #pragma unroll
        for (int q = 0; q < 8; ++q) u[q] = hb[(size_t)r[q] * 64 + lane];
        #pragma unroll
        for (int q = 0; q < 8; ++q) {
            const float nq = d[q] * dc;
            acc0 += bflo(u[q]) * nq;
            acc1 += bfhi(u[q]) * nq;
        }
    }
    for (; j + 2 <= m; j += 2) {
        const int r0 = ebuf[base + j], r1 = ebuf[base + j + 1];
        const float n0 = dinv[r0] * dc, n1 = dinv[r1] * dc;
        const unsigned u0 = hb[(size_t)r0 * 64 + lane];
        const unsigned u1 = hb[(size_t)r1 * 64 + lane];
        acc0 += bflo(u0) * n0; acc1 += bfhi(u0) * n0;
        acc0 += bflo(u1) * n1; acc1 += bfhi(u1) * n1;
    }
    if (j < m) {
        const int r = ebuf[base + j];
        const float nr = dinv[r] * dc;
        const unsigned u = hb[(size_t)r * 64 + lane];
        acc0 += bflo(u) * nr;
        acc1 += bfhi(u) * nr;
    }
    float2 o;
    o.x = fmaxf(acc0 + benc[lane * 2], 0.f);
    o.y = fmaxf(acc1 + benc[lane * 2 + 1], 0.f);
    *reinterpret_cast<float2*>(&z[(size_t)node * HDIM + lane * 2]) = o;
}

extern "C" void kernel_launch(void* const* d_in, const int* in_sizes, int n_in,
                              void* d_out, int out_size, void* d_ws, size_t ws_size,
                              hipStream_t stream) {
    const float* x     = (const float*)d_in[0];
    const int*   ei    = (const int*)d_in[1];
    const float* W_enc = (const float*)d_in[2];
    const float* b_enc = (const float*)d_in[3];
    const float* W_dec = (const float*)d_in[4];
    const float* b_dec = (const float*)d_in[5];

    const int N = in_sizes[0] / NDIM;   // 100000
    const int E = in_sizes[1] / 2;      // 1600000
    const int* row = ei;
    const int* col = ei + E;

    // workspace layout
    int*    cnt   = (int*)d_ws;
    int*    off   = cnt + NPAD;
    float*  dinv  = (float*)(off + NPAD);
    int*    bsum  = (int*)(dinv + NPAD);
    int*    bofs  = bsum + 1024;
    bf16_t* wbe   = (bf16_t*)(bofs + 1024);              // [HDIM][NDIM]
    bf16_t* wbd   = wbe + HDIM * NDIM;                   // [NDIM][HDIM]
    bf16_t* hb    = wbd + NDIM * HDIM;                   // [N][HDIM] bf16
    int*    ebuf  = (int*)(hb + (size_t)N * HDIM);       // [E]
    int*    rank  = ebuf + ((E + 3) & ~3);               // [E]

    float* z    = (float*)d_out;
    float* xrec = (float*)d_out + (size_t)N * HDIM;

    hipMemsetAsync(cnt, 0, NPAD * sizeof(int), stream);

    // pass A: degree count + per-edge rank
    k_count_rank<<<(E + 1023) / 1024, 256, 0, stream>>>(col, cnt, rank, E);

    // exclusive scan -> off (pass1 also emits dinv + weight casts)
    k_scan1<<<NSCAN + CASTBLKS, 256, 0, stream>>>(cnt, bsum, dinv, W_enc, wbe, W_dec, wbd);
    k_scan2<<<1, 128, 0, stream>>>(bsum, bofs, NSCAN);
    k_scan3<<<NSCAN, 256, 0, stream>>>(cnt, bofs, off);

    // pass B: atomic-free bucket scatter
    k_scatter<<<(E + 1023) / 1024, 256, 0, stream>>>(row, col, rank, off, ebuf, E);

    // h_bf16 = bf16(x @ W_enc^T)   (16 rows/wave, 64 rows/block, 1563 blocks)
    k_gemm_mfma<NDIM, HDIM, 1, true><<<(N + 63) / 64, 256, 0, stream>>>(x, wbe, nullptr, hb, N);

    // z = relu(D^-1/2 A D^-1/2 h + b_enc)
    k_agg<<<(N + 3) / 4, 256, 0, stream>>>(ebuf, off, cnt, dinv, (const unsigned*)hb, b_enc, z, N);

    // x_recon = z @ W_dec^T + b_dec   (16 rows/wave)
    k_gemm_mfma<HDIM, NDIM, 1, false><<<(N + 63) / 64, 256, 0, stream>>>(z, wbd, b_dec, xrec, N);
}

// Round 6
// 303.137 us; speedup vs baseline: 9.8566x; 1.1449x over previous
//
#include <hip/hip_runtime.h>
#include <hip/hip_bf16.h>

#define NDIM 256   // IN_DIM
#define HDIM 128   // HID
#define NPAD 100352          // N rounded up to 1024
#define NSCAN (NPAD / 1024)  // 98 scan blocks

typedef __bf16 bf16_t;
typedef bf16_t bf16x2 __attribute__((ext_vector_type(2)));
typedef bf16_t bf16x8 __attribute__((ext_vector_type(8)));
typedef float f32x4 __attribute__((ext_vector_type(4)));

// ---------------- prep: zero cnt + pack both weights into MFMA fragment order ----------------
// wp[(kk32*NF + nf)*64 + lane] (bf16x8) = W[(nf*16 + (lane&15))*K + kk32*32 + (lane>>4)*8 ..+8]
__global__ __launch_bounds__(256) void k_prep(int* __restrict__ cnt,
                                              const float* __restrict__ We, bf16_t* __restrict__ wpe,
                                              const float* __restrict__ Wd, bf16_t* __restrict__ wpd) {
    const int b = blockIdx.x, t = threadIdx.x;
    if (b < NSCAN) {
        const int4 zero4 = {0, 0, 0, 0};
        *reinterpret_cast<int4*>(&cnt[b * 1024 + t * 4]) = zero4;
        return;
    }
    const bool enc = b < NSCAN + 16;
    const int i = (enc ? (b - NSCAN) : (b - NSCAN - 16)) * 256 + t;  // 0..4095
    const int lane = i & 63;
    const int fr = lane & 15, kg = lane >> 4;
    int nf, kk32, K, NF;
    const float* W;
    bf16_t* wp;
    if (enc) { nf = (i >> 6) & 7;  kk32 = i >> 9;  K = NDIM; NF = 8;  W = We; wp = wpe; }
    else     { nf = (i >> 6) & 15; kk32 = i >> 10; K = HDIM; NF = 16; W = Wd; wp = wpd; }
    const float* src = &W[(size_t)(nf * 16 + fr) * K + kk32 * 32 + kg * 8];
    const f32x4 a0 = *reinterpret_cast<const f32x4*>(src);
    const f32x4 a1 = *reinterpret_cast<const f32x4*>(src + 4);
    bf16x8 o;
    o[0] = (bf16_t)a0[0]; o[1] = (bf16_t)a0[1]; o[2] = (bf16_t)a0[2]; o[3] = (bf16_t)a0[3];
    o[4] = (bf16_t)a1[0]; o[5] = (bf16_t)a1[1]; o[6] = (bf16_t)a1[2]; o[7] = (bf16_t)a1[3];
    reinterpret_cast<bf16x8*>(wp)[(kk32 * NF + nf) * 64 + lane] = o;
}

// ---------------- GEMM body (packed-fragment W): C[r][c] = sum_k A[r][k]*W[c][k] (+bias) ----------------
// mfma_f32_16x16x32_bf16: A lane l -> row l&15, k=(l>>4)*8+j; B lane l -> col l&15,
// same k; C/D lane l reg i -> col l&15, row (l>>4)*4+i. [m89]
template<int K, int NC, bool ABF16, bool OUT_BF16>
__device__ __forceinline__ void gemm_body(const int bid, const void* __restrict__ A,
                                          const bf16_t* __restrict__ Wp,
                                          const float* __restrict__ bias,
                                          void* __restrict__ Cout, const int nrows) {
    const int lane = threadIdx.x & 63;
    const int wv = threadIdx.x >> 6;     // 0..3
    const int fr = lane & 15;
    const int kg = lane >> 4;            // 0..3
    constexpr int NF = NC / 16, NK = K / 32;

    long long arow = (long long)bid * 64 + wv * 16 + fr;
    if (arow >= nrows) arow = nrows - 1;

    // hoist all A loads (independent, long-latency) before the MFMA ladder
    bf16x8 af[NK];
    if (ABF16) {
        const bf16_t* ab = (const bf16_t*)A + arow * K + kg * 8;
        #pragma unroll
        for (int k = 0; k < NK; ++k)
            af[k] = *reinterpret_cast<const bf16x8*>(ab + k * 32);
    } else {
        const float* ab = (const float*)A + arow * K + kg * 8;
        #pragma unroll
        for (int k = 0; k < NK; ++k) {
            const f32x4 a0 = *reinterpret_cast<const f32x4*>(ab + k * 32);
            const f32x4 a1 = *reinterpret_cast<const f32x4*>(ab + k * 32 + 4);
            af[k][0] = (bf16_t)a0[0]; af[k][1] = (bf16_t)a0[1];
            af[k][2] = (bf16_t)a0[2]; af[k][3] = (bf16_t)a0[3];
            af[k][4] = (bf16_t)a1[0]; af[k][5] = (bf16_t)a1[1];
            af[k][6] = (bf16_t)a1[2]; af[k][7] = (bf16_t)a1[3];
        }
    }

    const bf16x8* wp = reinterpret_cast<const bf16x8*>(Wp);
    f32x4 acc[NF];
    const f32x4 zero4 = {0.f, 0.f, 0.f, 0.f};
    #pragma unroll
    for (int nf = 0; nf < NF; ++nf) acc[nf] = zero4;

    #pragma unroll
    for (int k = 0; k < NK; ++k) {
        #pragma unroll
        for (int nf = 0; nf < NF; ++nf)
            acc[nf] = __builtin_amdgcn_mfma_f32_16x16x32_bf16(af[k], wp[(k * NF + nf) * 64 + lane], acc[nf], 0, 0, 0);
    }

    const long long rbase = (long long)bid * 64 + wv * 16 + kg * 4;
    #pragma unroll
    for (int nf = 0; nf < NF; ++nf) {
        const int c = nf * 16 + fr;
        const float bv = bias ? bias[c] : 0.f;
        #pragma unroll
        for (int i = 0; i < 4; ++i) {
            const long long r = rbase + i;
            if (r < nrows) {
                const float v = acc[nf][i] + bv;
                if (OUT_BF16) ((bf16_t*)Cout)[r * NC + c] = (bf16_t)v;
                else          ((float*)Cout)[r * NC + c] = v;
            }
        }
    }
}

// ---------------- count_rank body (atomic w/ return, 4 edges/thread) ----------------
__device__ __forceinline__ void count_body(const int bid, const int* __restrict__ col,
                                           int* __restrict__ cnt, int* __restrict__ rank,
                                           const int E) {
    const int idx = bid * 256 + threadIdx.x;
    const int e0 = idx * 4;
    if (e0 >= E) return;
    if (e0 + 4 <= E) {
        const int4 c = *reinterpret_cast<const int4*>(&col[e0]);
        int4 r;
        r.x = atomicAdd(&cnt[c.x], 1);
        r.y = atomicAdd(&cnt[c.y], 1);
        r.z = atomicAdd(&cnt[c.z], 1);
        r.w = atomicAdd(&cnt[c.w], 1);
        *reinterpret_cast<int4*>(&rank[e0]) = r;
    } else {
        for (int e = e0; e < E; ++e) rank[e] = atomicAdd(&cnt[col[e]], 1);
    }
}

// ---------------- fused: GEMM1 (even blocks) + count_rank (odd blocks) ----------------
__global__ __launch_bounds__(256) void k_fused(const float* __restrict__ x,
                                               const bf16_t* __restrict__ wpe,
                                               bf16_t* __restrict__ hb, const int nrows,
                                               const int* __restrict__ col,
                                               int* __restrict__ cnt,
                                               int* __restrict__ rank, const int E) {
    const int b = blockIdx.x;
    if (b & 1) count_body(b >> 1, col, cnt, rank, E);
    else       gemm_body<NDIM, HDIM, false, true>(b >> 1, x, wpe, nullptr, hb, nrows);
}

// ---------------- scan pass 1 (+ fused dinv) ----------------
__global__ __launch_bounds__(256) void k_scan1(const int* __restrict__ cnt,
                                               int* __restrict__ bsum,
                                               float* __restrict__ dinv) {
    __shared__ int s[256];
    const int b = blockIdx.x, t = threadIdx.x;
    const int4 v = *reinterpret_cast<const int4*>(&cnt[b * 1024 + t * 4]);
    float4 dv;
    dv.x = rsqrtf((float)(v.x + 1));
    dv.y = rsqrtf((float)(v.y + 1));
    dv.z = rsqrtf((float)(v.z + 1));
    dv.w = rsqrtf((float)(v.w + 1));
    *reinterpret_cast<float4*>(&dinv[b * 1024 + t * 4]) = dv;
    s[t] = v.x + v.y + v.z + v.w;
    __syncthreads();
    for (int d = 128; d > 0; d >>= 1) {
        if (t < d) s[t] += s[t + d];
        __syncthreads();
    }
    if (t == 0) bsum[b] = s[0];
}

__global__ __launch_bounds__(128) void k_scan2(const int* __restrict__ bsum,
                                               int* __restrict__ bofs, int nb) {
    __shared__ int s[128];
    int t = threadIdx.x;
    int v = (t < nb) ? bsum[t] : 0;
    s[t] = v;
    __syncthreads();
    for (int d = 1; d < 128; d <<= 1) {
        int x = (t >= d) ? s[t - d] : 0;
        __syncthreads();
        s[t] += x;
        __syncthreads();
    }
    if (t < nb) bofs[t] = s[t] - v;  // exclusive
}

__global__ __launch_bounds__(256) void k_scan3(const int* __restrict__ cnt,
                                               const int* __restrict__ bofs,
                                               int* __restrict__ off) {
    __shared__ int s[256];
    int b = blockIdx.x, t = threadIdx.x;
    const int4 v = *reinterpret_cast<const int4*>(&cnt[b * 1024 + t * 4]);
    int tsum = v.x + v.y + v.z + v.w;
    s[t] = tsum;
    __syncthreads();
    for (int d = 1; d < 256; d <<= 1) {
        int x = (t >= d) ? s[t - d] : 0;
        __syncthreads();
        s[t] += x;
        __syncthreads();
    }
    int excl = s[t] - tsum + bofs[b];
    int4 o;
    o.x = excl; o.y = excl + v.x; o.z = o.y + v.y; o.w = o.z + v.z;
    *reinterpret_cast<int4*>(&off[b * 1024 + t * 4]) = o;
}

// ---------------- atomic-free scatter (4 edges/thread) ----------------
__global__ __launch_bounds__(256) void k_scatter(const int* __restrict__ row,
                                                 const int* __restrict__ col,
                                                 const int* __restrict__ rank,
                                                 const int* __restrict__ off,
                                                 int* __restrict__ ebuf, int E) {
    const int idx = blockIdx.x * 256 + threadIdx.x;
    const int e0 = idx * 4;
    if (e0 >= E) return;
    if (e0 + 4 <= E) {
        const int4 c = *reinterpret_cast<const int4*>(&col[e0]);
        const int4 r = *reinterpret_cast<const int4*>(&row[e0]);
        const int4 k = *reinterpret_cast<const int4*>(&rank[e0]);
        const int o0 = off[c.x], o1 = off[c.y], o2 = off[c.z], o3 = off[c.w];
        ebuf[o0 + k.x] = r.x;
        ebuf[o1 + k.y] = r.y;
        ebuf[o2 + k.z] = r.z;
        ebuf[o3 + k.w] = r.w;
    } else {
        for (int e = e0; e < E; ++e) ebuf[off[col[e]] + rank[e]] = row[e];
    }
}

// ---------------- gather-aggregate + self-loop + bias + relu (+ bf16 copy of z) ----------------
__device__ __forceinline__ float bflo(unsigned u) { return __uint_as_float(u << 16); }
__device__ __forceinline__ float bfhi(unsigned u) { return __uint_as_float(u & 0xffff0000u); }

__global__ __launch_bounds__(256) void k_agg(const int* __restrict__ ebuf,
                                             const int* __restrict__ off,
                                             const int* __restrict__ cnt,
                                             const float* __restrict__ dinv,
                                             const unsigned* __restrict__ hb,  // bf16 pairs [N][64]
                                             const float* __restrict__ benc,
                                             float* __restrict__ z,
                                             bf16_t* __restrict__ zb, int n) {
    const int node = blockIdx.x * 4 + (threadIdx.x >> 6);
    const int lane = threadIdx.x & 63;
    if (node >= n) return;
    const float dc = dinv[node];
    const unsigned hself = hb[(size_t)node * 64 + lane];
    float acc0 = bflo(hself) * (dc * dc);
    float acc1 = bfhi(hself) * (dc * dc);
    const int base = off[node], m = cnt[node];
    int j = 0;
    for (; j + 16 <= m; j += 16) {
        int r[16]; float d[16]; unsigned u[16];
        #pragma unroll
        for (int q = 0; q < 16; ++q) r[q] = ebuf[base + j + q];
        #pragma unroll
        for (int q = 0; q < 16; ++q) u[q] = hb[(size_t)r[q] * 64 + lane];
        #pragma unroll
        for (int q = 0; q < 16; ++q) d[q] = dinv[r[q]];
        #pragma unroll
        for (int q = 0; q < 16; ++q) {
            const float nq = d[q] * dc;
            acc0 += bflo(u[q]) * nq;
            acc1 += bfhi(u[q]) * nq;
        }
    }
    for (; j + 4 <= m; j += 4) {
        int r[4]; float d[4]; unsigned u[4];
        #pragma unroll
        for (int q = 0; q < 4; ++q) r[q] = ebuf[base + j + q];
        #pragma unroll
        for (int q = 0; q < 4; ++q) u[q] = hb[(size_t)r[q] * 64 + lane];
        #pragma unroll
        for (int q = 0; q < 4; ++q) d[q] = dinv[r[q]];
        #pragma unroll
        for (int q = 0; q < 4; ++q) {
            const float nq = d[q] * dc;
            acc0 += bflo(u[q]) * nq;
            acc1 += bfhi(u[q]) * nq;
        }
    }
    for (; j < m; ++j) {
        const int r = ebuf[base + j];
        const float nr = dinv[r] * dc;
        const unsigned u = hb[(size_t)r * 64 + lane];
        acc0 += bflo(u) * nr;
        acc1 += bfhi(u) * nr;
    }
    float2 o;
    o.x = fmaxf(acc0 + benc[lane * 2], 0.f);
    o.y = fmaxf(acc1 + benc[lane * 2 + 1], 0.f);
    *reinterpret_cast<float2*>(&z[(size_t)node * HDIM + lane * 2]) = o;
    bf16x2 ob;
    ob[0] = (bf16_t)o.x;
    ob[1] = (bf16_t)o.y;
    *reinterpret_cast<bf16x2*>(&zb[(size_t)node * HDIM + lane * 2]) = ob;
}

// ---------------- GEMM2 standalone ----------------
__global__ __launch_bounds__(256) void k_gemm2(const bf16_t* __restrict__ zb,
                                               const bf16_t* __restrict__ wpd,
                                               const float* __restrict__ bias,
                                               float* __restrict__ xrec, const int nrows) {
    gemm_body<HDIM, NDIM, true, false>(blockIdx.x, zb, wpd, bias, xrec, nrows);
}

extern "C" void kernel_launch(void* const* d_in, const int* in_sizes, int n_in,
                              void* d_out, int out_size, void* d_ws, size_t ws_size,
                              hipStream_t stream) {
    const float* x     = (const float*)d_in[0];
    const int*   ei    = (const int*)d_in[1];
    const float* W_enc = (const float*)d_in[2];
    const float* b_enc = (const float*)d_in[3];
    const float* W_dec = (const float*)d_in[4];
    const float* b_dec = (const float*)d_in[5];

    const int N = in_sizes[0] / NDIM;   // 100000
    const int E = in_sizes[1] / 2;      // 1600000
    const int* row = ei;
    const int* col = ei + E;

    // workspace layout
    int*    cnt   = (int*)d_ws;
    int*    off   = cnt + NPAD;
    float*  dinv  = (float*)(off + NPAD);
    int*    bsum  = (int*)(dinv + NPAD);
    int*    bofs  = bsum + 1024;
    bf16_t* wpe   = (bf16_t*)(bofs + 1024);              // packed [8][8][64][8]
    bf16_t* wpd   = wpe + HDIM * NDIM;                   // packed [4][16][64][8]
    bf16_t* hb    = wpd + NDIM * HDIM;                   // [N][HDIM] bf16
    int*    ebuf  = (int*)(hb + (size_t)N * HDIM);       // [E]
    int*    rank  = ebuf + ((E + 3) & ~3);               // [E]  (dead after scatter)
    bf16_t* zb    = (bf16_t*)rank;                       // [N][HDIM] bf16, overlays rank

    float* z    = (float*)d_out;
    float* xrec = (float*)d_out + (size_t)N * HDIM;

    // 1) zero cnt + pack weights
    k_prep<<<NSCAN + 32, 256, 0, stream>>>(cnt, W_enc, wpe, W_dec, wpd);

    // 2) fused: h_bf16 = bf16(x @ W_enc^T)  ||  degree count + per-edge rank
    const int gemm1_blocks = (N + 63) / 64;                 // 1563
    const int count_blocks = (E + 1023) / 1024;             // 1563
    k_fused<<<2 * ((gemm1_blocks > count_blocks) ? gemm1_blocks : count_blocks), 256, 0, stream>>>(
        x, wpe, hb, N, col, cnt, rank, E);

    // 3) exclusive scan -> off (pass1 also emits dinv)
    k_scan1<<<NSCAN, 256, 0, stream>>>(cnt, bsum, dinv);
    k_scan2<<<1, 128, 0, stream>>>(bsum, bofs, NSCAN);
    k_scan3<<<NSCAN, 256, 0, stream>>>(cnt, bofs, off);

    // 4) atomic-free bucket scatter
    k_scatter<<<(E + 1023) / 1024, 256, 0, stream>>>(row, col, rank, off, ebuf, E);

    // 5) z = relu(D^-1/2 A D^-1/2 h + b_enc)  (+ bf16 copy zb; rank is dead now)
    k_agg<<<(N + 3) / 4, 256, 0, stream>>>(ebuf, off, cnt, dinv, (const unsigned*)hb, b_enc, z, zb, N);

    // 6) x_recon = zb @ W_dec^T + b_dec
    k_gemm2<<<(N + 63) / 64, 256, 0, stream>>>(zb, wpd, b_dec, xrec, N);
}

// Round 7
// 300.943 us; speedup vs baseline: 9.9284x; 1.0073x over previous
//
#include <hip/hip_runtime.h>
#include <hip/hip_bf16.h>

#define NDIM 256   // IN_DIM
#define HDIM 128   // HID
#define NPAD 100352          // N rounded up to 1024
#define NSCAN (NPAD / 1024)  // 98 scan blocks
#define LDS1_STRIDE 264      // bf16 row stride for GEMM1 staging (256 + 8 pad)
#define LDS2_STRIDE 136      // bf16 row stride for GEMM2 staging (128 + 8 pad)

typedef __bf16 bf16_t;
typedef bf16_t bf16x2 __attribute__((ext_vector_type(2)));
typedef bf16_t bf16x4 __attribute__((ext_vector_type(4)));
typedef bf16_t bf16x8 __attribute__((ext_vector_type(8)));
typedef float f32x4 __attribute__((ext_vector_type(4)));

// ---------------- prep: zero cnt + pack both weights into MFMA fragment order ----------------
// wp[(kk32*NF + nf)*64 + lane] (bf16x8) = W[(nf*16 + (lane&15))*K + kk32*32 + (lane>>4)*8 ..+8]
__global__ __launch_bounds__(256) void k_prep(int* __restrict__ cnt,
                                              const float* __restrict__ We, bf16_t* __restrict__ wpe,
                                              const float* __restrict__ Wd, bf16_t* __restrict__ wpd) {
    const int b = blockIdx.x, t = threadIdx.x;
    if (b < NSCAN) {
        const int4 zero4 = {0, 0, 0, 0};
        *reinterpret_cast<int4*>(&cnt[b * 1024 + t * 4]) = zero4;
        return;
    }
    const bool enc = b < NSCAN + 16;
    const int i = (enc ? (b - NSCAN) : (b - NSCAN - 16)) * 256 + t;  // 0..4095
    const int lane = i & 63;
    const int fr = lane & 15, kg = lane >> 4;
    int nf, kk32, K, NF;
    const float* W;
    bf16_t* wp;
    if (enc) { nf = (i >> 6) & 7;  kk32 = i >> 9;  K = NDIM; NF = 8;  W = We; wp = wpe; }
    else     { nf = (i >> 6) & 15; kk32 = i >> 10; K = HDIM; NF = 16; W = Wd; wp = wpd; }
    const float* src = &W[(size_t)(nf * 16 + fr) * K + kk32 * 32 + kg * 8];
    const f32x4 a0 = *reinterpret_cast<const f32x4*>(src);
    const f32x4 a1 = *reinterpret_cast<const f32x4*>(src + 4);
    bf16x8 o;
    o[0] = (bf16_t)a0[0]; o[1] = (bf16_t)a0[1]; o[2] = (bf16_t)a0[2]; o[3] = (bf16_t)a0[3];
    o[4] = (bf16_t)a1[0]; o[5] = (bf16_t)a1[1]; o[6] = (bf16_t)a1[2]; o[7] = (bf16_t)a1[3];
    reinterpret_cast<bf16x8*>(wp)[(kk32 * NF + nf) * 64 + lane] = o;
}

// ---------------- MFMA ladder + epilogue (af already in regs) ----------------
// mfma_f32_16x16x32_bf16: A lane l -> row l&15, k=(l>>4)*8+j; B lane l -> col l&15,
// same k; C/D lane l reg i -> col l&15, row (l>>4)*4+i. [m89]
template<int K, int NC, bool OUT_BF16>
__device__ __forceinline__ void mfma_epi(const bf16x8* af,
                                         const bf16_t* __restrict__ Wp,
                                         const float* __restrict__ bias,
                                         void* __restrict__ Cout,
                                         const int bid, const int nrows) {
    const int lane = threadIdx.x & 63;
    const int wv = threadIdx.x >> 6;
    const int fr = lane & 15;
    const int kg = lane >> 4;
    constexpr int NF = NC / 16, NK = K / 32;

    const bf16x8* wp = reinterpret_cast<const bf16x8*>(Wp);
    f32x4 acc[NF];
    const f32x4 zero4 = {0.f, 0.f, 0.f, 0.f};
    #pragma unroll
    for (int nf = 0; nf < NF; ++nf) acc[nf] = zero4;

    #pragma unroll
    for (int k = 0; k < NK; ++k) {
        #pragma unroll
        for (int nf = 0; nf < NF; ++nf)
            acc[nf] = __builtin_amdgcn_mfma_f32_16x16x32_bf16(af[k], wp[(k * NF + nf) * 64 + lane], acc[nf], 0, 0, 0);
    }

    const long long rbase = (long long)bid * 64 + wv * 16 + kg * 4;
    #pragma unroll
    for (int nf = 0; nf < NF; ++nf) {
        const int c = nf * 16 + fr;
        const float bv = bias ? bias[c] : 0.f;
        #pragma unroll
        for (int i = 0; i < 4; ++i) {
            const long long r = rbase + i;
            if (r < nrows) {
                const float v = acc[nf][i] + bv;
                if (OUT_BF16) ((bf16_t*)Cout)[r * NC + c] = (bf16_t)v;
                else          ((float*)Cout)[r * NC + c] = v;
            }
        }
    }
}

// ---------------- GEMM1 body: LDS-staged A (f32 -> bf16), 64 rows/block ----------------
__device__ __forceinline__ void gemm1_body(const int bid, const float* __restrict__ x,
                                           const bf16_t* __restrict__ wpe,
                                           bf16_t* __restrict__ hb, const int nrows,
                                           bf16_t* lds) {
    const int t = threadIdx.x;
    const long long rowbase = (long long)bid * 64;
    // stage: 64 rows x 256 f32, coalesced (one instr = one full 1KB row)
    #pragma unroll
    for (int p = 0; p < 16; ++p) {
        const int s = p * 256 + t;          // float4 slot
        const int r = s >> 6, c4 = s & 63;
        long long gr = rowbase + r;
        if (gr >= nrows) gr = nrows - 1;
        const f32x4 v = *reinterpret_cast<const f32x4*>(&x[gr * NDIM + c4 * 4]);
        bf16x4 o;
        o[0] = (bf16_t)v[0]; o[1] = (bf16_t)v[1]; o[2] = (bf16_t)v[2]; o[3] = (bf16_t)v[3];
        *reinterpret_cast<bf16x4*>(&lds[r * LDS1_STRIDE + c4 * 4]) = o;
    }
    __syncthreads();
    const int lane = t & 63, wv = t >> 6, fr = lane & 15, kg = lane >> 4;
    bf16x8 af[8];
    #pragma unroll
    for (int k = 0; k < 8; ++k)
        af[k] = *reinterpret_cast<const bf16x8*>(&lds[(wv * 16 + fr) * LDS1_STRIDE + k * 32 + kg * 8]);
    mfma_epi<NDIM, HDIM, true>(af, wpe, nullptr, hb, bid, nrows);
}

// ---------------- count_rank body (atomic w/ return, 4 edges/thread) ----------------
__device__ __forceinline__ void count_body(const int bid, const int* __restrict__ col,
                                           int* __restrict__ cnt, int* __restrict__ rank,
                                           const int E) {
    const int idx = bid * 256 + threadIdx.x;
    const int e0 = idx * 4;
    if (e0 >= E) return;
    if (e0 + 4 <= E) {
        const int4 c = *reinterpret_cast<const int4*>(&col[e0]);
        int4 r;
        r.x = atomicAdd(&cnt[c.x], 1);
        r.y = atomicAdd(&cnt[c.y], 1);
        r.z = atomicAdd(&cnt[c.z], 1);
        r.w = atomicAdd(&cnt[c.w], 1);
        *reinterpret_cast<int4*>(&rank[e0]) = r;
    } else {
        for (int e = e0; e < E; ++e) rank[e] = atomicAdd(&cnt[col[e]], 1);
    }
}

// ---------------- fused: GEMM1 (blocks < G1) + count_rank (rest) ----------------
__global__ __launch_bounds__(256) void k_fused(const float* __restrict__ x,
                                               const bf16_t* __restrict__ wpe,
                                               bf16_t* __restrict__ hb, const int nrows,
                                               const int* __restrict__ col,
                                               int* __restrict__ cnt,
                                               int* __restrict__ rank, const int E,
                                               const int G1) {
    __shared__ __align__(16) bf16_t lds[64 * LDS1_STRIDE];
    const int b = blockIdx.x;
    if (b < G1) gemm1_body(b, x, wpe, hb, nrows, lds);
    else        count_body(b - G1, col, cnt, rank, E);
}

// ---------------- scan pass 1 (+ fused dinv) ----------------
__global__ __launch_bounds__(256) void k_scan1(const int* __restrict__ cnt,
                                               int* __restrict__ bsum,
                                               float* __restrict__ dinv) {
    __shared__ int s[256];
    const int b = blockIdx.x, t = threadIdx.x;
    const int4 v = *reinterpret_cast<const int4*>(&cnt[b * 1024 + t * 4]);
    float4 dv;
    dv.x = rsqrtf((float)(v.x + 1));
    dv.y = rsqrtf((float)(v.y + 1));
    dv.z = rsqrtf((float)(v.z + 1));
    dv.w = rsqrtf((float)(v.w + 1));
    *reinterpret_cast<float4*>(&dinv[b * 1024 + t * 4]) = dv;
    s[t] = v.x + v.y + v.z + v.w;
    __syncthreads();
    for (int d = 128; d > 0; d >>= 1) {
        if (t < d) s[t] += s[t + d];
        __syncthreads();
    }
    if (t == 0) bsum[b] = s[0];
}

__global__ __launch_bounds__(128) void k_scan2(const int* __restrict__ bsum,
                                               int* __restrict__ bofs, int nb) {
    __shared__ int s[128];
    int t = threadIdx.x;
    int v = (t < nb) ? bsum[t] : 0;
    s[t] = v;
    __syncthreads();
    for (int d = 1; d < 128; d <<= 1) {
        int x = (t >= d) ? s[t - d] : 0;
        __syncthreads();
        s[t] += x;
        __syncthreads();
    }
    if (t < nb) bofs[t] = s[t] - v;  // exclusive
}

__global__ __launch_bounds__(256) void k_scan3(const int* __restrict__ cnt,
                                               const int* __restrict__ bofs,
                                               int* __restrict__ off) {
    __shared__ int s[256];
    int b = blockIdx.x, t = threadIdx.x;
    const int4 v = *reinterpret_cast<const int4*>(&cnt[b * 1024 + t * 4]);
    int tsum = v.x + v.y + v.z + v.w;
    s[t] = tsum;
    __syncthreads();
    for (int d = 1; d < 256; d <<= 1) {
        int x = (t >= d) ? s[t - d] : 0;
        __syncthreads();
        s[t] += x;
        __syncthreads();
    }
    int excl = s[t] - tsum + bofs[b];
    int4 o;
    o.x = excl; o.y = excl + v.x; o.z = o.y + v.y; o.w = o.z + v.z;
    *reinterpret_cast<int4*>(&off[b * 1024 + t * 4]) = o;
}

// ---------------- atomic-free scatter (4 edges/thread) ----------------
__global__ __launch_bounds__(256) void k_scatter(const int* __restrict__ row,
                                                 const int* __restrict__ col,
                                                 const int* __restrict__ rank,
                                                 const int* __restrict__ off,
                                                 int* __restrict__ ebuf, int E) {
    const int idx = blockIdx.x * 256 + threadIdx.x;
    const int e0 = idx * 4;
    if (e0 >= E) return;
    if (e0 + 4 <= E) {
        const int4 c = *reinterpret_cast<const int4*>(&col[e0]);
        const int4 r = *reinterpret_cast<const int4*>(&row[e0]);
        const int4 k = *reinterpret_cast<const int4*>(&rank[e0]);
        const int o0 = off[c.x], o1 = off[c.y], o2 = off[c.z], o3 = off[c.w];
        ebuf[o0 + k.x] = r.x;
        ebuf[o1 + k.y] = r.y;
        ebuf[o2 + k.z] = r.z;
        ebuf[o3 + k.w] = r.w;
    } else {
        for (int e = e0; e < E; ++e) ebuf[off[col[e]] + rank[e]] = row[e];
    }
}

// ---------------- gather-aggregate + self-loop + bias + relu (+ bf16 copy of z) ----------------
__device__ __forceinline__ float bflo(unsigned u) { return __uint_as_float(u << 16); }
__device__ __forceinline__ float bfhi(unsigned u) { return __uint_as_float(u & 0xffff0000u); }

__global__ __launch_bounds__(256) void k_agg(const int* __restrict__ ebuf,
                                             const int* __restrict__ off,
                                             const int* __restrict__ cnt,
                                             const float* __restrict__ dinv,
                                             const unsigned* __restrict__ hb,  // bf16 pairs [N][64]
                                             const float* __restrict__ benc,
                                             float* __restrict__ z,
                                             bf16_t* __restrict__ zb, int n) {
    const int node = blockIdx.x * 4 + (threadIdx.x >> 6);
    const int lane = threadIdx.x & 63;
    if (node >= n) return;
    const float dc = dinv[node];
    const unsigned hself = hb[(size_t)node * 64 + lane];
    float acc0 = bflo(hself) * (dc * dc);
    float acc1 = bfhi(hself) * (dc * dc);
    const int base = off[node], m = cnt[node];
    int j = 0;
    for (; j + 16 <= m; j += 16) {
        int r[16]; float d[16]; unsigned u[16];
        #pragma unroll
        for (int q = 0; q < 16; ++q) r[q] = ebuf[base + j + q];
        #pragma unroll
        for (int q = 0; q < 16; ++q) u[q] = hb[(size_t)r[q] * 64 + lane];
        #pragma unroll
        for (int q = 0; q < 16; ++q) d[q] = dinv[r[q]];
        #pragma unroll
        for (int q = 0; q < 16; ++q) {
            const float nq = d[q] * dc;
            acc0 += bflo(u[q]) * nq;
            acc1 += bfhi(u[q]) * nq;
        }
    }
    for (; j + 4 <= m; j += 4) {
        int r[4]; float d[4]; unsigned u[4];
        #pragma unroll
        for (int q = 0; q < 4; ++q) r[q] = ebuf[base + j + q];
        #pragma unroll
        for (int q = 0; q < 4; ++q) u[q] = hb[(size_t)r[q] * 64 + lane];
        #pragma unroll
        for (int q = 0; q < 4; ++q) d[q] = dinv[r[q]];
        #pragma unroll
        for (int q = 0; q < 4; ++q) {
            const float nq = d[q] * dc;
            acc0 += bflo(u[q]) * nq;
            acc1 += bfhi(u[q]) * nq;
        }
    }
    for (; j < m; ++j) {
        const int r = ebuf[base + j];
        const float nr = dinv[r] * dc;
        const unsigned u = hb[(size_t)r * 64 + lane];
        acc0 += bflo(u) * nr;
        acc1 += bfhi(u) * nr;
    }
    float2 o;
    o.x = fmaxf(acc0 + benc[lane * 2], 0.f);
    o.y = fmaxf(acc1 + benc[lane * 2 + 1], 0.f);
    *reinterpret_cast<float2*>(&z[(size_t)node * HDIM + lane * 2]) = o;
    bf16x2 ob;
    ob[0] = (bf16_t)o.x;
    ob[1] = (bf16_t)o.y;
    *reinterpret_cast<bf16x2*>(&zb[(size_t)node * HDIM + lane * 2]) = ob;
}

// ---------------- GEMM2: LDS-staged A (bf16), 64 rows/block ----------------
__global__ __launch_bounds__(256) void k_gemm2(const bf16_t* __restrict__ zb,
                                               const bf16_t* __restrict__ wpd,
                                               const float* __restrict__ bias,
                                               float* __restrict__ xrec, const int nrows) {
    __shared__ __align__(16) bf16_t lds[64 * LDS2_STRIDE];
    const int t = threadIdx.x;
    const long long rowbase = (long long)blockIdx.x * 64;
    #pragma unroll
    for (int p = 0; p < 4; ++p) {
        const int s = p * 256 + t;       // bf16x8 slot
        const int r = s >> 4, c8 = s & 15;
        long long gr = rowbase + r;
        if (gr >= nrows) gr = nrows - 1;
        const bf16x8 v = *reinterpret_cast<const bf16x8*>(&zb[gr * HDIM + c8 * 8]);
        *reinterpret_cast<bf16x8*>(&lds[r * LDS2_STRIDE + c8 * 8]) = v;
    }
    __syncthreads();
    const int lane = t & 63, wv = t >> 6, fr = lane & 15, kg = lane >> 4;
    bf16x8 af[4];
    #pragma unroll
    for (int k = 0; k < 4; ++k)
        af[k] = *reinterpret_cast<const bf16x8*>(&lds[(wv * 16 + fr) * LDS2_STRIDE + k * 32 + kg * 8]);
    mfma_epi<HDIM, NDIM, false>(af, wpd, bias, xrec, blockIdx.x, nrows);
}

extern "C" void kernel_launch(void* const* d_in, const int* in_sizes, int n_in,
                              void* d_out, int out_size, void* d_ws, size_t ws_size,
                              hipStream_t stream) {
    const float* x     = (const float*)d_in[0];
    const int*   ei    = (const int*)d_in[1];
    const float* W_enc = (const float*)d_in[2];
    const float* b_enc = (const float*)d_in[3];
    const float* W_dec = (const float*)d_in[4];
    const float* b_dec = (const float*)d_in[5];

    const int N = in_sizes[0] / NDIM;   // 100000
    const int E = in_sizes[1] / 2;      // 1600000
    const int* row = ei;
    const int* col = ei + E;

    // workspace layout
    int*    cnt   = (int*)d_ws;
    int*    off   = cnt + NPAD;
    float*  dinv  = (float*)(off + NPAD);
    int*    bsum  = (int*)(dinv + NPAD);
    int*    bofs  = bsum + 1024;
    bf16_t* wpe   = (bf16_t*)(bofs + 1024);              // packed [8][8][64][8]
    bf16_t* wpd   = wpe + HDIM * NDIM;                   // packed [4][16][64][8]
    bf16_t* hb    = wpd + NDIM * HDIM;                   // [N][HDIM] bf16
    int*    ebuf  = (int*)(hb + (size_t)N * HDIM);       // [E]
    int*    rank  = ebuf + ((E + 3) & ~3);               // [E]  (dead after scatter)
    bf16_t* zb    = (bf16_t*)rank;                       // [N][HDIM] bf16, overlays rank

    float* z    = (float*)d_out;
    float* xrec = (float*)d_out + (size_t)N * HDIM;

    // 1) zero cnt + pack weights
    k_prep<<<NSCAN + 32, 256, 0, stream>>>(cnt, W_enc, wpe, W_dec, wpd);

    // 2) fused: h_bf16 = bf16(x @ W_enc^T)  ||  degree count + per-edge rank
    const int gemm1_blocks = (N + 63) / 64;                 // 1563
    const int count_blocks = (E + 1023) / 1024;             // 1563
    k_fused<<<gemm1_blocks + count_blocks, 256, 0, stream>>>(
        x, wpe, hb, N, col, cnt, rank, E, gemm1_blocks);

    // 3) exclusive scan -> off (pass1 also emits dinv)
    k_scan1<<<NSCAN, 256, 0, stream>>>(cnt, bsum, dinv);
    k_scan2<<<1, 128, 0, stream>>>(bsum, bofs, NSCAN);
    k_scan3<<<NSCAN, 256, 0, stream>>>(cnt, bofs, off);

    // 4) atomic-free bucket scatter
    k_scatter<<<(E + 1023) / 1024, 256, 0, stream>>>(row, col, rank, off, ebuf, E);

    // 5) z = relu(D^-1/2 A D^-1/2 h + b_enc)  (+ bf16 copy zb; rank is dead now)
    k_agg<<<(N + 3) / 4, 256, 0, stream>>>(ebuf, off, cnt, dinv, (const unsigned*)hb, b_enc, z, zb, N);

    // 6) x_recon = zb @ W_dec^T + b_dec
    k_gemm2<<<(N + 63) / 64, 256, 0, stream>>>(zb, wpd, b_dec, xrec, N);
}